// Round 8
// baseline (1328.345 us; speedup 1.0000x reference)
//
#include <hip/hip_runtime.h>
#include <cmath>

typedef __attribute__((ext_vector_type(8))) short bf16x8;
typedef __attribute__((ext_vector_type(4))) float f32x4;

#define TBLSZ (1 << 18)
#define TMASK (TBLSZ - 1)
#define N_ENTRIES ((long long)16 * TBLSZ)
// ws layout: [tbl_bf: 4M x 8B = 32MB][wbf: 9216 bf16 (pad 32KB)][feats: 1M x 128B = 128MB]
#define WS_TBL_BYTES (N_ENTRIES * 8)
#define WS_W_BYTES   (32 * 1024)
#define WS_TBL_NEED  (WS_TBL_BYTES + WS_W_BYTES)
#define WS_FEAT_BYTES ((long long)(1 << 20) * 128)
#define WS_FULL_NEED (WS_TBL_NEED + WS_FEAT_BYTES)

struct ResArgs { float r[16]; };

__device__ __forceinline__ unsigned short f2bf(float f) {
    unsigned u = __float_as_uint(f);
    u += 0x7fffu + ((u >> 16) & 1u);   // RTNE
    return (unsigned short)(u >> 16);
}

// ---- one hash-grid level, bf16 tables: returns packed {f0|f1, f2|f3} ----
__device__ __forceinline__ uint2 enc_level_bf16(const uint2* __restrict__ tbl,
                                                float px, float py, float pz, float res) {
    float xl = px * res, yl = py * res, zl = pz * res;
    float fx = floorf(xl), fy = floorf(yl), fz = floorf(zl);
    float tx = xl - fx, ty = yl - fy, tz = zl - fz;
    unsigned cx = (unsigned)(int)fx, cy = (unsigned)(int)fy, cz = (unsigned)(int)fz;
    unsigned hx[2] = { cx, cx + 1u };
    unsigned hy[2] = { cy * 2654435761u, cy * 2654435761u + 2654435761u };
    unsigned hz[2] = { cz * 805459861u,  cz * 805459861u + 805459861u };
    float wx[2] = { 1.f - tx, tx }, wy[2] = { 1.f - ty, ty }, wz[2] = { 1.f - tz, tz };
    float a0 = 0.f, a1 = 0.f, a2 = 0.f, a3 = 0.f;
    #pragma unroll
    for (int c = 0; c < 8; ++c) {
        const int ox = (c >> 2) & 1, oy = (c >> 1) & 1, oz = c & 1;
        unsigned h = (hx[ox] ^ hy[oy] ^ hz[oz]) & TMASK;
        uint2 v = tbl[h];
        float ww = wx[ox] * wy[oy] * wz[oz];
        a0 = fmaf(ww, __uint_as_float(v.x << 16), a0);
        a1 = fmaf(ww, __uint_as_float(v.x & 0xffff0000u), a1);
        a2 = fmaf(ww, __uint_as_float(v.y << 16), a2);
        a3 = fmaf(ww, __uint_as_float(v.y & 0xffff0000u), a3);
    }
    uint2 pk;
    pk.x = (unsigned)f2bf(a0) | ((unsigned)f2bf(a1) << 16);
    pk.y = (unsigned)f2bf(a2) | ((unsigned)f2bf(a3) << 16);
    return pk;
}

__device__ __forceinline__ uint2 enc_level_f32(const float4* __restrict__ tbl,
                                               float px, float py, float pz, float res) {
    float xl = px * res, yl = py * res, zl = pz * res;
    float fx = floorf(xl), fy = floorf(yl), fz = floorf(zl);
    float tx = xl - fx, ty = yl - fy, tz = zl - fz;
    unsigned cx = (unsigned)(int)fx, cy = (unsigned)(int)fy, cz = (unsigned)(int)fz;
    unsigned hx[2] = { cx, cx + 1u };
    unsigned hy[2] = { cy * 2654435761u, cy * 2654435761u + 2654435761u };
    unsigned hz[2] = { cz * 805459861u,  cz * 805459861u + 805459861u };
    float wx[2] = { 1.f - tx, tx }, wy[2] = { 1.f - ty, ty }, wz[2] = { 1.f - tz, tz };
    float a0 = 0.f, a1 = 0.f, a2 = 0.f, a3 = 0.f;
    #pragma unroll
    for (int c = 0; c < 8; ++c) {
        const int ox = (c >> 2) & 1, oy = (c >> 1) & 1, oz = c & 1;
        unsigned h = (hx[ox] ^ hy[oy] ^ hz[oz]) & TMASK;
        float4 v = tbl[h];
        float ww = wx[ox] * wy[oy] * wz[oz];
        a0 = fmaf(ww, v.x, a0); a1 = fmaf(ww, v.y, a1);
        a2 = fmaf(ww, v.z, a2); a3 = fmaf(ww, v.w, a3);
    }
    uint2 pk;
    pk.x = (unsigned)f2bf(a0) | ((unsigned)f2bf(a1) << 16);
    pk.y = (unsigned)f2bf(a2) | ((unsigned)f2bf(a3) << 16);
    return pk;
}

// ---- prologue: f32 tables/weights -> bf16 in ws ----
__global__ __launch_bounds__(256) void conv_tables(
    const float4* __restrict__ tables,
    const float* __restrict__ W1, const float* __restrict__ W2,
    const float* __restrict__ W3,
    uint2* __restrict__ tbl, unsigned short* __restrict__ wbf)
{
    const int t = threadIdx.x;
    for (long long i = (long long)blockIdx.x * 256 + t; i < N_ENTRIES;
         i += (long long)gridDim.x * 256) {
        float4 v = tables[i];
        uint2 p;
        p.x = (unsigned)f2bf(v.x) | ((unsigned)f2bf(v.y) << 16);
        p.y = (unsigned)f2bf(v.z) | ((unsigned)f2bf(v.w) << 16);
        tbl[i] = p;
    }
    if (blockIdx.x == 0) {
        const int base = t * 16;
        #pragma unroll
        for (int e = 0; e < 16; ++e) wbf[base + e] = f2bf(W1[base + e]);
        #pragma unroll
        for (int e = 0; e < 16; ++e) wbf[4096 + base + e] = f2bf(W2[base + e]);
        if (t < 32) {
            #pragma unroll
            for (int e = 0; e < 16; ++e) wbf[8192 + base + e] = f2bf(W3[base + e]);
        } else if (t < 64) {
            #pragma unroll
            for (int e = 0; e < 16; ++e) wbf[8192 + base + e] = 0;
        }
    }
}

// ---- phase 1 (split): pure gather/encode, no LDS, no MFMA state ----
__global__ __launch_bounds__(256, 8) void encode_kernel(
    const float* __restrict__ ipos,
    const uint2* __restrict__ tbl_bf,
    uint4* __restrict__ feats,           // [pt][8] uint4  (= [pt][64] bf16)
    ResArgs ra)
{
    const long long gi = (long long)blockIdx.x * 256 + threadIdx.x;
    const float px = ipos[gi * 3 + 0];
    const float py = ipos[gi * 3 + 1];
    const float pz = ipos[gi * 3 + 2];
    #pragma unroll 1
    for (int p = 0; p < 8; ++p) {        // two independent levels in flight (16 gathers)
        uint2 e0 = enc_level_bf16(tbl_bf + (size_t)(2 * p) * TBLSZ,     px, py, pz, ra.r[2 * p]);
        uint2 e1 = enc_level_bf16(tbl_bf + (size_t)(2 * p + 1) * TBLSZ, px, py, pz, ra.r[2 * p + 1]);
        uint4 v; v.x = e0.x; v.y = e0.y; v.z = e1.x; v.w = e1.y;
        feats[gi * 8 + p] = v;
    }
}

// ---- phase 2 (split): MLP via MFMA, B-frags straight from feats ----
__global__ __launch_bounds__(256, 4) void mlp_kernel(
    const uint4* __restrict__ feats,
    const unsigned short* __restrict__ wbf,
    const float* __restrict__ b1, const float* __restrict__ b2,
    const float* __restrict__ b3,
    float* __restrict__ out)
{
    __shared__ __attribute__((aligned(16))) unsigned short xb[4][8][64][8];
    const int t   = threadIdx.x;
    const int w   = t >> 6;
    const int l   = t & 63;
    const int q   = l >> 4;
    const int l16 = l & 15;
    const long long gbase = (long long)blockIdx.x * 256 + w * 64;

    // load X B-frags for this wave straight from feats (strided 16B, L2-warm)
    bf16x8 xf[8];
    #pragma unroll
    for (int n = 0; n < 4; ++n) {
        #pragma unroll
        for (int kb = 0; kb < 2; ++kb) {
            uint4 v = feats[(gbase + n * 16 + l16) * 8 + kb * 4 + q];
            xf[n * 2 + kb] = *(const bf16x8*)&v;
        }
    }

    // layer 1: frags from registers; layers 2: from xb
    #pragma unroll 1
    for (int layer = 0; layer < 2; ++layer) {
        const float* bptr = layer ? b2 : b1;
        const unsigned short* wp = wbf + layer * 4096;
        f32x4 acc[4][4];
        #pragma unroll
        for (int m = 0; m < 4; ++m) {
            bf16x8 af0 = *(const bf16x8*)(wp + (m * 16 + l16) * 64 +  0 + q * 8);
            bf16x8 af1 = *(const bf16x8*)(wp + (m * 16 + l16) * 64 + 32 + q * 8);
            #pragma unroll
            for (int n = 0; n < 4; ++n) {
                f32x4 d = { 0.f, 0.f, 0.f, 0.f };
                if (layer == 0) {
                    d = __builtin_amdgcn_mfma_f32_16x16x32_bf16(af0, xf[n * 2 + 0], d, 0, 0, 0);
                    d = __builtin_amdgcn_mfma_f32_16x16x32_bf16(af1, xf[n * 2 + 1], d, 0, 0, 0);
                } else {
                    d = __builtin_amdgcn_mfma_f32_16x16x32_bf16(af0, *(const bf16x8*)&xb[w][n * 2 + 0][l][0], d, 0, 0, 0);
                    d = __builtin_amdgcn_mfma_f32_16x16x32_bf16(af1, *(const bf16x8*)&xb[w][n * 2 + 1][l][0], d, 0, 0, 0);
                }
                acc[m][n] = d;
            }
        }
        #pragma unroll
        for (int m = 0; m < 4; ++m) {
            #pragma unroll
            for (int n = 0; n < 4; ++n) {
                #pragma unroll
                for (int rr = 0; rr < 4; rr += 2) {
                    const int j0 = m * 16 + q * 4 + rr;
                    float v0 = fmaxf(acc[m][n][rr]     + bptr[j0],     0.f);
                    float v1 = fmaxf(acc[m][n][rr + 1] + bptr[j0 + 1], 0.f);
                    unsigned pk = (unsigned)f2bf(v0) | ((unsigned)f2bf(v1) << 16);
                    const int blk = n * 2 + (j0 >> 5);
                    const int lp  = l16 + 16 * ((j0 & 31) >> 3);
                    *(unsigned*)&xb[w][blk][lp][j0 & 7] = pk;
                }
            }
        }
    }

    // layer 3 + sigmoid, coalesced f32x4 stores
    {
        bf16x8 af0 = *(const bf16x8*)(wbf + 8192 + l16 * 64 +  0 + q * 8);
        bf16x8 af1 = *(const bf16x8*)(wbf + 8192 + l16 * 64 + 32 + q * 8);
        #pragma unroll
        for (int n = 0; n < 4; ++n) {
            f32x4 d = { 0.f, 0.f, 0.f, 0.f };
            d = __builtin_amdgcn_mfma_f32_16x16x32_bf16(af0, *(const bf16x8*)&xb[w][n * 2 + 0][l][0], d, 0, 0, 0);
            d = __builtin_amdgcn_mfma_f32_16x16x32_bf16(af1, *(const bf16x8*)&xb[w][n * 2 + 1][l][0], d, 0, 0, 0);
            if (q < 2) {
                f32x4 o;
                #pragma unroll
                for (int r = 0; r < 4; ++r) {
                    float v = d[r] + b3[q * 4 + r];
                    o[r] = 1.f / (1.f + __expf(-v));
                }
                *(f32x4*)&out[(gbase + n * 16 + l16) * 8 + q * 4] = o;
            }
        }
    }
}

// ---- fallback: fused kernel (round-3 structure), BF via ws or pure f32 ----
template<bool BF>
__global__ __launch_bounds__(256, 4) void hashgrid_mlp(
    const float* __restrict__ ipos,
    const float4* __restrict__ tables_f32,
    const uint2* __restrict__ tbl_bf,
    const unsigned short* __restrict__ wbf,
    const float* __restrict__ W1, const float* __restrict__ W2,
    const float* __restrict__ W3,
    const float* __restrict__ b1, const float* __restrict__ b2,
    const float* __restrict__ b3,
    float* __restrict__ out, ResArgs ra)
{
    __shared__ __attribute__((aligned(16))) unsigned short xb[4][8][64][8];
    const int t   = threadIdx.x;
    const int w   = t >> 6;
    const int l   = t & 63;
    const int q   = l >> 4;
    const int l16 = l & 15;

    {
        const long long gi = (long long)blockIdx.x * 256 + t;
        const float px = ipos[gi * 3 + 0];
        const float py = ipos[gi * 3 + 1];
        const float pz = ipos[gi * 3 + 2];
        const int n2base = (l >> 4) * 2;
        #pragma unroll 2
        for (int lvl = 0; lvl < 16; ++lvl) {
            uint2 pk = BF ? enc_level_bf16(tbl_bf + (size_t)lvl * TBLSZ, px, py, pz, ra.r[lvl])
                          : enc_level_f32(tables_f32 + (size_t)lvl * TBLSZ, px, py, pz, ra.r[lvl]);
            const int blk = n2base + (lvl >> 3);
            const int lp  = l16 + 16 * ((lvl & 7) >> 1);
            *(uint2*)&xb[w][blk][lp][(lvl & 1) * 4] = pk;
        }
    }

    #pragma unroll 1
    for (int layer = 0; layer < 2; ++layer) {
        const float* bptr = layer ? b2 : b1;
        f32x4 acc[4][4];
        #pragma unroll
        for (int m = 0; m < 4; ++m) {
            bf16x8 af0, af1;
            if constexpr (BF) {
                const unsigned short* wp = wbf + layer * 4096;
                af0 = *(const bf16x8*)(wp + (m * 16 + l16) * 64 +  0 + q * 8);
                af1 = *(const bf16x8*)(wp + (m * 16 + l16) * 64 + 32 + q * 8);
            } else {
                const float* Wp = layer ? W2 : W1;
                const float* r0 = Wp + (m * 16 + l16) * 64 + q * 8;
                float4 a = *(const float4*)(r0), b = *(const float4*)(r0 + 4);
                float4 c = *(const float4*)(r0 + 32), e = *(const float4*)(r0 + 36);
                af0[0]=f2bf(a.x);af0[1]=f2bf(a.y);af0[2]=f2bf(a.z);af0[3]=f2bf(a.w);
                af0[4]=f2bf(b.x);af0[5]=f2bf(b.y);af0[6]=f2bf(b.z);af0[7]=f2bf(b.w);
                af1[0]=f2bf(c.x);af1[1]=f2bf(c.y);af1[2]=f2bf(c.z);af1[3]=f2bf(c.w);
                af1[4]=f2bf(e.x);af1[5]=f2bf(e.y);af1[6]=f2bf(e.z);af1[7]=f2bf(e.w);
            }
            #pragma unroll
            for (int n = 0; n < 4; ++n) {
                f32x4 d = { 0.f, 0.f, 0.f, 0.f };
                d = __builtin_amdgcn_mfma_f32_16x16x32_bf16(af0, *(const bf16x8*)&xb[w][n * 2 + 0][l][0], d, 0, 0, 0);
                d = __builtin_amdgcn_mfma_f32_16x16x32_bf16(af1, *(const bf16x8*)&xb[w][n * 2 + 1][l][0], d, 0, 0, 0);
                acc[m][n] = d;
            }
        }
        #pragma unroll
        for (int m = 0; m < 4; ++m) {
            #pragma unroll
            for (int n = 0; n < 4; ++n) {
                #pragma unroll
                for (int rr = 0; rr < 4; rr += 2) {
                    const int j0 = m * 16 + q * 4 + rr;
                    float v0 = fmaxf(acc[m][n][rr]     + bptr[j0],     0.f);
                    float v1 = fmaxf(acc[m][n][rr + 1] + bptr[j0 + 1], 0.f);
                    unsigned pk = (unsigned)f2bf(v0) | ((unsigned)f2bf(v1) << 16);
                    const int blk = n * 2 + (j0 >> 5);
                    const int lp  = l16 + 16 * ((j0 & 31) >> 3);
                    *(unsigned*)&xb[w][blk][lp][j0 & 7] = pk;
                }
            }
        }
    }

    {
        bf16x8 af0, af1;
        if constexpr (BF) {
            af0 = *(const bf16x8*)(wbf + 8192 + l16 * 64 +  0 + q * 8);
            af1 = *(const bf16x8*)(wbf + 8192 + l16 * 64 + 32 + q * 8);
        } else {
            if (l16 < 8) {
                const float* r0 = W3 + l16 * 64 + q * 8;
                float4 a = *(const float4*)(r0), b = *(const float4*)(r0 + 4);
                float4 c = *(const float4*)(r0 + 32), e = *(const float4*)(r0 + 36);
                af0[0]=f2bf(a.x);af0[1]=f2bf(a.y);af0[2]=f2bf(a.z);af0[3]=f2bf(a.w);
                af0[4]=f2bf(b.x);af0[5]=f2bf(b.y);af0[6]=f2bf(b.z);af0[7]=f2bf(b.w);
                af1[0]=f2bf(c.x);af1[1]=f2bf(c.y);af1[2]=f2bf(c.z);af1[3]=f2bf(c.w);
                af1[4]=f2bf(e.x);af1[5]=f2bf(e.y);af1[6]=f2bf(e.z);af1[7]=f2bf(e.w);
            } else {
                af0 = bf16x8{0,0,0,0,0,0,0,0};
                af1 = bf16x8{0,0,0,0,0,0,0,0};
            }
        }
        const long long gbase = (long long)blockIdx.x * 256 + w * 64;
        #pragma unroll
        for (int n = 0; n < 4; ++n) {
            f32x4 d = { 0.f, 0.f, 0.f, 0.f };
            d = __builtin_amdgcn_mfma_f32_16x16x32_bf16(af0, *(const bf16x8*)&xb[w][n * 2 + 0][l][0], d, 0, 0, 0);
            d = __builtin_amdgcn_mfma_f32_16x16x32_bf16(af1, *(const bf16x8*)&xb[w][n * 2 + 1][l][0], d, 0, 0, 0);
            if (q < 2) {
                f32x4 o;
                #pragma unroll
                for (int r = 0; r < 4; ++r) {
                    float v = d[r] + b3[q * 4 + r];
                    o[r] = 1.f / (1.f + __expf(-v));
                }
                *(f32x4*)&out[(gbase + n * 16 + l16) * 8 + q * 4] = o;
            }
        }
    }
}

extern "C" void kernel_launch(void* const* d_in, const int* in_sizes, int n_in,
                              void* d_out, int out_size, void* d_ws, size_t ws_size,
                              hipStream_t stream) {
    const float*  ipos   = (const float*)d_in[0];
    const float4* tables = (const float4*)d_in[1];
    const float*  W1 = (const float*)d_in[2];
    const float*  b1 = (const float*)d_in[3];
    const float*  W2 = (const float*)d_in[4];
    const float*  b2 = (const float*)d_in[5];
    const float*  W3 = (const float*)d_in[6];
    const float*  b3 = (const float*)d_in[7];
    float* out = (float*)d_out;

    ResArgs ra;
    const double g = exp((log(512.0) - log(16.0)) / 15.0);   // matches Python libm
    for (int lvl = 0; lvl < 16; ++lvl)
        ra.r[lvl] = (float)floor(16.0 * pow(g, (double)lvl));

    const int n = in_sizes[0] / 3;           // 1<<20

    uint2* tbl_bf = (uint2*)d_ws;
    unsigned short* wbf = (unsigned short*)((char*)d_ws + WS_TBL_BYTES);
    uint4* feats = (uint4*)((char*)d_ws + WS_TBL_NEED);

    if (ws_size >= (size_t)WS_FULL_NEED) {   // ws_size constant per harness -> deterministic
        conv_tables<<<dim3(4096), dim3(256), 0, stream>>>(tables, W1, W2, W3, tbl_bf, wbf);
        encode_kernel<<<dim3(n / 256), dim3(256), 0, stream>>>(ipos, tbl_bf, feats, ra);
        mlp_kernel<<<dim3(n / 256), dim3(256), 0, stream>>>(feats, wbf, b1, b2, b3, out);
    } else if (ws_size >= (size_t)WS_TBL_NEED) {
        conv_tables<<<dim3(4096), dim3(256), 0, stream>>>(tables, W1, W2, W3, tbl_bf, wbf);
        hashgrid_mlp<true><<<dim3(n / 256), dim3(256), 0, stream>>>(
            ipos, tables, tbl_bf, wbf, W1, W2, W3, b1, b2, b3, out, ra);
    } else {
        hashgrid_mlp<false><<<dim3(n / 256), dim3(256), 0, stream>>>(
            ipos, tables, tbl_bf, wbf, W1, W2, W3, b1, b2, b3, out, ra);
    }
}

// Round 9
// 693.415 us; speedup vs baseline: 1.9157x; 1.9157x over previous
//
#include <hip/hip_runtime.h>
#include <cmath>

typedef __attribute__((ext_vector_type(8))) short bf16x8;
typedef __attribute__((ext_vector_type(4))) float f32x4;

#define TBLSZ (1 << 18)
#define TMASK (TBLSZ - 1)
#define N_ENTRIES ((long long)16 * TBLSZ)
// ws layout: [tbl_bf: 4M x 8B = 32MB][wbf: 9216 bf16 (pad 32KB)][feats_lm: 16 x 1M x 8B = 128MB]
#define WS_TBL_BYTES (N_ENTRIES * 8)
#define WS_W_BYTES   (32 * 1024)
#define WS_TBL_NEED  (WS_TBL_BYTES + WS_W_BYTES)
#define WS_FEAT_BYTES ((long long)(1 << 20) * 128)
#define WS_FULL_NEED (WS_TBL_NEED + WS_FEAT_BYTES)

struct ResArgs { float r[16]; };

__device__ __forceinline__ unsigned short f2bf(float f) {
    unsigned u = __float_as_uint(f);
    u += 0x7fffu + ((u >> 16) & 1u);   // RTNE
    return (unsigned short)(u >> 16);
}

// ---- one hash-grid level, bf16 tables: returns packed {f0|f1, f2|f3} ----
__device__ __forceinline__ uint2 enc_level_bf16(const uint2* __restrict__ tbl,
                                                float px, float py, float pz, float res) {
    float xl = px * res, yl = py * res, zl = pz * res;
    float fx = floorf(xl), fy = floorf(yl), fz = floorf(zl);
    float tx = xl - fx, ty = yl - fy, tz = zl - fz;
    unsigned cx = (unsigned)(int)fx, cy = (unsigned)(int)fy, cz = (unsigned)(int)fz;
    unsigned hx[2] = { cx, cx + 1u };
    unsigned hy[2] = { cy * 2654435761u, cy * 2654435761u + 2654435761u };
    unsigned hz[2] = { cz * 805459861u,  cz * 805459861u + 805459861u };
    float wx[2] = { 1.f - tx, tx }, wy[2] = { 1.f - ty, ty }, wz[2] = { 1.f - tz, tz };
    float a0 = 0.f, a1 = 0.f, a2 = 0.f, a3 = 0.f;
    #pragma unroll
    for (int c = 0; c < 8; ++c) {
        const int ox = (c >> 2) & 1, oy = (c >> 1) & 1, oz = c & 1;
        unsigned h = (hx[ox] ^ hy[oy] ^ hz[oz]) & TMASK;
        uint2 v = tbl[h];
        float ww = wx[ox] * wy[oy] * wz[oz];
        a0 = fmaf(ww, __uint_as_float(v.x << 16), a0);
        a1 = fmaf(ww, __uint_as_float(v.x & 0xffff0000u), a1);
        a2 = fmaf(ww, __uint_as_float(v.y << 16), a2);
        a3 = fmaf(ww, __uint_as_float(v.y & 0xffff0000u), a3);
    }
    uint2 pk;
    pk.x = (unsigned)f2bf(a0) | ((unsigned)f2bf(a1) << 16);
    pk.y = (unsigned)f2bf(a2) | ((unsigned)f2bf(a3) << 16);
    return pk;
}

__device__ __forceinline__ uint2 enc_level_f32(const float4* __restrict__ tbl,
                                               float px, float py, float pz, float res) {
    float xl = px * res, yl = py * res, zl = pz * res;
    float fx = floorf(xl), fy = floorf(yl), fz = floorf(zl);
    float tx = xl - fx, ty = yl - fy, tz = zl - fz;
    unsigned cx = (unsigned)(int)fx, cy = (unsigned)(int)fy, cz = (unsigned)(int)fz;
    unsigned hx[2] = { cx, cx + 1u };
    unsigned hy[2] = { cy * 2654435761u, cy * 2654435761u + 2654435761u };
    unsigned hz[2] = { cz * 805459861u,  cz * 805459861u + 805459861u };
    float wx[2] = { 1.f - tx, tx }, wy[2] = { 1.f - ty, ty }, wz[2] = { 1.f - tz, tz };
    float a0 = 0.f, a1 = 0.f, a2 = 0.f, a3 = 0.f;
    #pragma unroll
    for (int c = 0; c < 8; ++c) {
        const int ox = (c >> 2) & 1, oy = (c >> 1) & 1, oz = c & 1;
        unsigned h = (hx[ox] ^ hy[oy] ^ hz[oz]) & TMASK;
        float4 v = tbl[h];
        float ww = wx[ox] * wy[oy] * wz[oz];
        a0 = fmaf(ww, v.x, a0); a1 = fmaf(ww, v.y, a1);
        a2 = fmaf(ww, v.z, a2); a3 = fmaf(ww, v.w, a3);
    }
    uint2 pk;
    pk.x = (unsigned)f2bf(a0) | ((unsigned)f2bf(a1) << 16);
    pk.y = (unsigned)f2bf(a2) | ((unsigned)f2bf(a3) << 16);
    return pk;
}

// ---- prologue: f32 tables/weights -> bf16 in ws ----
__global__ __launch_bounds__(256) void conv_tables(
    const float4* __restrict__ tables,
    const float* __restrict__ W1, const float* __restrict__ W2,
    const float* __restrict__ W3,
    uint2* __restrict__ tbl, unsigned short* __restrict__ wbf)
{
    const int t = threadIdx.x;
    for (long long i = (long long)blockIdx.x * 256 + t; i < N_ENTRIES;
         i += (long long)gridDim.x * 256) {
        float4 v = tables[i];
        uint2 p;
        p.x = (unsigned)f2bf(v.x) | ((unsigned)f2bf(v.y) << 16);
        p.y = (unsigned)f2bf(v.z) | ((unsigned)f2bf(v.w) << 16);
        tbl[i] = p;
    }
    if (blockIdx.x == 0) {
        const int base = t * 16;
        #pragma unroll
        for (int e = 0; e < 16; ++e) wbf[base + e] = f2bf(W1[base + e]);
        #pragma unroll
        for (int e = 0; e < 16; ++e) wbf[4096 + base + e] = f2bf(W2[base + e]);
        if (t < 32) {
            #pragma unroll
            for (int e = 0; e < 16; ++e) wbf[8192 + base + e] = f2bf(W3[base + e]);
        } else if (t < 64) {
            #pragma unroll
            for (int e = 0; e < 16; ++e) wbf[8192 + base + e] = 0;
        }
    }
}

// ---- phase 1: LEVEL-MAJOR encode. One block = one level x 256 points.
// Dispatch order is level-major, so at any instant each XCD's L2 holds
// essentially one level's 2MB bf16 table -> gathers become L2 hits.
__global__ __launch_bounds__(256) void encode_lm(
    const float* __restrict__ ipos,
    const uint2* __restrict__ tbl_bf,
    uint2* __restrict__ feats_lm,        // [16][npts] uint2 (4 bf16 feats)
    int chunks, int npts, ResArgs ra)
{
    const unsigned bid = blockIdx.x;
    const int lvl   = bid / (unsigned)chunks;
    const int chunk = bid - lvl * chunks;
    const long long pt = (long long)chunk * 256 + threadIdx.x;
    const float px = ipos[pt * 3 + 0];
    const float py = ipos[pt * 3 + 1];
    const float pz = ipos[pt * 3 + 2];
    uint2 pk = enc_level_bf16(tbl_bf + (size_t)lvl * TBLSZ, px, py, pz, ra.r[lvl]);
    feats_lm[(size_t)lvl * npts + pt] = pk;   // coalesced 8B store
}

// ---- phase 2: MLP via MFMA; gather 16 levels per point (coalesced), LDS transpose ----
__global__ __launch_bounds__(256, 4) void mlp_lm(
    const uint2* __restrict__ feats_lm,
    const unsigned short* __restrict__ wbf,
    const float* __restrict__ b1, const float* __restrict__ b2,
    const float* __restrict__ b3,
    float* __restrict__ out, int npts)
{
    __shared__ __attribute__((aligned(16))) unsigned short xb[4][8][64][8];
    const int t   = threadIdx.x;
    const int w   = t >> 6;
    const int l   = t & 63;
    const int q   = l >> 4;
    const int l16 = l & 15;
    const long long gi = (long long)blockIdx.x * 256 + t;
    const int n2base = (l >> 4) * 2;

    #pragma unroll
    for (int lvl = 0; lvl < 16; ++lvl) {
        uint2 pk = feats_lm[(size_t)lvl * npts + gi];
        const int blk = n2base + (lvl >> 3);
        const int lp  = l16 + 16 * ((lvl & 7) >> 1);
        *(uint2*)&xb[w][blk][lp][(lvl & 1) * 4] = pk;
    }
    // no barrier: each wave reads only its own xb[w] blocks (DS in-order per wave)

    #pragma unroll 1
    for (int layer = 0; layer < 2; ++layer) {
        const float* bptr = layer ? b2 : b1;
        const unsigned short* wp = wbf + layer * 4096;
        f32x4 acc[4][4];
        #pragma unroll
        for (int m = 0; m < 4; ++m) {
            bf16x8 af0 = *(const bf16x8*)(wp + (m * 16 + l16) * 64 +  0 + q * 8);
            bf16x8 af1 = *(const bf16x8*)(wp + (m * 16 + l16) * 64 + 32 + q * 8);
            #pragma unroll
            for (int n = 0; n < 4; ++n) {
                f32x4 d = { 0.f, 0.f, 0.f, 0.f };
                d = __builtin_amdgcn_mfma_f32_16x16x32_bf16(af0, *(const bf16x8*)&xb[w][n * 2 + 0][l][0], d, 0, 0, 0);
                d = __builtin_amdgcn_mfma_f32_16x16x32_bf16(af1, *(const bf16x8*)&xb[w][n * 2 + 1][l][0], d, 0, 0, 0);
                acc[m][n] = d;
            }
        }
        #pragma unroll
        for (int m = 0; m < 4; ++m) {
            #pragma unroll
            for (int n = 0; n < 4; ++n) {
                #pragma unroll
                for (int rr = 0; rr < 4; rr += 2) {
                    const int j0 = m * 16 + q * 4 + rr;
                    float v0 = fmaxf(acc[m][n][rr]     + bptr[j0],     0.f);
                    float v1 = fmaxf(acc[m][n][rr + 1] + bptr[j0 + 1], 0.f);
                    unsigned pk = (unsigned)f2bf(v0) | ((unsigned)f2bf(v1) << 16);
                    const int blk = n * 2 + (j0 >> 5);
                    const int lp  = l16 + 16 * ((j0 & 31) >> 3);
                    *(unsigned*)&xb[w][blk][lp][j0 & 7] = pk;
                }
            }
        }
    }

    // layer 3 + sigmoid, coalesced f32x4 stores
    {
        bf16x8 af0 = *(const bf16x8*)(wbf + 8192 + l16 * 64 +  0 + q * 8);
        bf16x8 af1 = *(const bf16x8*)(wbf + 8192 + l16 * 64 + 32 + q * 8);
        const long long gbase = (long long)blockIdx.x * 256 + w * 64;
        #pragma unroll
        for (int n = 0; n < 4; ++n) {
            f32x4 d = { 0.f, 0.f, 0.f, 0.f };
            d = __builtin_amdgcn_mfma_f32_16x16x32_bf16(af0, *(const bf16x8*)&xb[w][n * 2 + 0][l][0], d, 0, 0, 0);
            d = __builtin_amdgcn_mfma_f32_16x16x32_bf16(af1, *(const bf16x8*)&xb[w][n * 2 + 1][l][0], d, 0, 0, 0);
            if (q < 2) {
                f32x4 o;
                #pragma unroll
                for (int r = 0; r < 4; ++r) {
                    float v = d[r] + b3[q * 4 + r];
                    o[r] = 1.f / (1.f + __expf(-v));
                }
                *(f32x4*)&out[(gbase + n * 16 + l16) * 8 + q * 4] = o;
            }
        }
    }
}

// ---- fallback: fused kernel (round-3 structure), BF via ws or pure f32 ----
template<bool BF>
__global__ __launch_bounds__(256, 4) void hashgrid_mlp(
    const float* __restrict__ ipos,
    const float4* __restrict__ tables_f32,
    const uint2* __restrict__ tbl_bf,
    const unsigned short* __restrict__ wbf,
    const float* __restrict__ W1, const float* __restrict__ W2,
    const float* __restrict__ W3,
    const float* __restrict__ b1, const float* __restrict__ b2,
    const float* __restrict__ b3,
    float* __restrict__ out, ResArgs ra)
{
    __shared__ __attribute__((aligned(16))) unsigned short xb[4][8][64][8];
    const int t   = threadIdx.x;
    const int w   = t >> 6;
    const int l   = t & 63;
    const int q   = l >> 4;
    const int l16 = l & 15;

    {
        const long long gi = (long long)blockIdx.x * 256 + t;
        const float px = ipos[gi * 3 + 0];
        const float py = ipos[gi * 3 + 1];
        const float pz = ipos[gi * 3 + 2];
        const int n2base = (l >> 4) * 2;
        #pragma unroll 2
        for (int lvl = 0; lvl < 16; ++lvl) {
            uint2 pk = BF ? enc_level_bf16(tbl_bf + (size_t)lvl * TBLSZ, px, py, pz, ra.r[lvl])
                          : enc_level_f32(tables_f32 + (size_t)lvl * TBLSZ, px, py, pz, ra.r[lvl]);
            const int blk = n2base + (lvl >> 3);
            const int lp  = l16 + 16 * ((lvl & 7) >> 1);
            *(uint2*)&xb[w][blk][lp][(lvl & 1) * 4] = pk;
        }
    }

    #pragma unroll 1
    for (int layer = 0; layer < 2; ++layer) {
        const float* bptr = layer ? b2 : b1;
        f32x4 acc[4][4];
        #pragma unroll
        for (int m = 0; m < 4; ++m) {
            bf16x8 af0, af1;
            if constexpr (BF) {
                const unsigned short* wp = wbf + layer * 4096;
                af0 = *(const bf16x8*)(wp + (m * 16 + l16) * 64 +  0 + q * 8);
                af1 = *(const bf16x8*)(wp + (m * 16 + l16) * 64 + 32 + q * 8);
            } else {
                const float* Wp = layer ? W2 : W1;
                const float* r0 = Wp + (m * 16 + l16) * 64 + q * 8;
                float4 a = *(const float4*)(r0), b = *(const float4*)(r0 + 4);
                float4 c = *(const float4*)(r0 + 32), e = *(const float4*)(r0 + 36);
                af0[0]=f2bf(a.x);af0[1]=f2bf(a.y);af0[2]=f2bf(a.z);af0[3]=f2bf(a.w);
                af0[4]=f2bf(b.x);af0[5]=f2bf(b.y);af0[6]=f2bf(b.z);af0[7]=f2bf(b.w);
                af1[0]=f2bf(c.x);af1[1]=f2bf(c.y);af1[2]=f2bf(c.z);af1[3]=f2bf(c.w);
                af1[4]=f2bf(e.x);af1[5]=f2bf(e.y);af1[6]=f2bf(e.z);af1[7]=f2bf(e.w);
            }
            #pragma unroll
            for (int n = 0; n < 4; ++n) {
                f32x4 d = { 0.f, 0.f, 0.f, 0.f };
                d = __builtin_amdgcn_mfma_f32_16x16x32_bf16(af0, *(const bf16x8*)&xb[w][n * 2 + 0][l][0], d, 0, 0, 0);
                d = __builtin_amdgcn_mfma_f32_16x16x32_bf16(af1, *(const bf16x8*)&xb[w][n * 2 + 1][l][0], d, 0, 0, 0);
                acc[m][n] = d;
            }
        }
        #pragma unroll
        for (int m = 0; m < 4; ++m) {
            #pragma unroll
            for (int n = 0; n < 4; ++n) {
                #pragma unroll
                for (int rr = 0; rr < 4; rr += 2) {
                    const int j0 = m * 16 + q * 4 + rr;
                    float v0 = fmaxf(acc[m][n][rr]     + bptr[j0],     0.f);
                    float v1 = fmaxf(acc[m][n][rr + 1] + bptr[j0 + 1], 0.f);
                    unsigned pk = (unsigned)f2bf(v0) | ((unsigned)f2bf(v1) << 16);
                    const int blk = n * 2 + (j0 >> 5);
                    const int lp  = l16 + 16 * ((j0 & 31) >> 3);
                    *(unsigned*)&xb[w][blk][lp][j0 & 7] = pk;
                }
            }
        }
    }

    {
        bf16x8 af0, af1;
        if constexpr (BF) {
            af0 = *(const bf16x8*)(wbf + 8192 + l16 * 64 +  0 + q * 8);
            af1 = *(const bf16x8*)(wbf + 8192 + l16 * 64 + 32 + q * 8);
        } else {
            if (l16 < 8) {
                const float* r0 = W3 + l16 * 64 + q * 8;
                float4 a = *(const float4*)(r0), b = *(const float4*)(r0 + 4);
                float4 c = *(const float4*)(r0 + 32), e = *(const float4*)(r0 + 36);
                af0[0]=f2bf(a.x);af0[1]=f2bf(a.y);af0[2]=f2bf(a.z);af0[3]=f2bf(a.w);
                af0[4]=f2bf(b.x);af0[5]=f2bf(b.y);af0[6]=f2bf(b.z);af0[7]=f2bf(b.w);
                af1[0]=f2bf(c.x);af1[1]=f2bf(c.y);af1[2]=f2bf(c.z);af1[3]=f2bf(c.w);
                af1[4]=f2bf(e.x);af1[5]=f2bf(e.y);af1[6]=f2bf(e.z);af1[7]=f2bf(e.w);
            } else {
                af0 = bf16x8{0,0,0,0,0,0,0,0};
                af1 = bf16x8{0,0,0,0,0,0,0,0};
            }
        }
        const long long gbase = (long long)blockIdx.x * 256 + w * 64;
        #pragma unroll
        for (int n = 0; n < 4; ++n) {
            f32x4 d = { 0.f, 0.f, 0.f, 0.f };
            d = __builtin_amdgcn_mfma_f32_16x16x32_bf16(af0, *(const bf16x8*)&xb[w][n * 2 + 0][l][0], d, 0, 0, 0);
            d = __builtin_amdgcn_mfma_f32_16x16x32_bf16(af1, *(const bf16x8*)&xb[w][n * 2 + 1][l][0], d, 0, 0, 0);
            if (q < 2) {
                f32x4 o;
                #pragma unroll
                for (int r = 0; r < 4; ++r) {
                    float v = d[r] + b3[q * 4 + r];
                    o[r] = 1.f / (1.f + __expf(-v));
                }
                *(f32x4*)&out[(gbase + n * 16 + l16) * 8 + q * 4] = o;
            }
        }
    }
}

extern "C" void kernel_launch(void* const* d_in, const int* in_sizes, int n_in,
                              void* d_out, int out_size, void* d_ws, size_t ws_size,
                              hipStream_t stream) {
    const float*  ipos   = (const float*)d_in[0];
    const float4* tables = (const float4*)d_in[1];
    const float*  W1 = (const float*)d_in[2];
    const float*  b1 = (const float*)d_in[3];
    const float*  W2 = (const float*)d_in[4];
    const float*  b2 = (const float*)d_in[5];
    const float*  W3 = (const float*)d_in[6];
    const float*  b3 = (const float*)d_in[7];
    float* out = (float*)d_out;

    ResArgs ra;
    const double g = exp((log(512.0) - log(16.0)) / 15.0);   // matches Python libm
    for (int lvl = 0; lvl < 16; ++lvl)
        ra.r[lvl] = (float)floor(16.0 * pow(g, (double)lvl));

    const int n = in_sizes[0] / 3;           // 1<<20

    uint2* tbl_bf = (uint2*)d_ws;
    unsigned short* wbf = (unsigned short*)((char*)d_ws + WS_TBL_BYTES);
    uint2* feats_lm = (uint2*)((char*)d_ws + WS_TBL_NEED);

    if (ws_size >= (size_t)WS_FULL_NEED) {   // ws_size constant per harness -> deterministic
        const int chunks = n / 256;          // 4096
        conv_tables<<<dim3(4096), dim3(256), 0, stream>>>(tables, W1, W2, W3, tbl_bf, wbf);
        encode_lm<<<dim3(16 * chunks), dim3(256), 0, stream>>>(ipos, tbl_bf, feats_lm, chunks, n, ra);
        mlp_lm<<<dim3(chunks), dim3(256), 0, stream>>>(feats_lm, wbf, b1, b2, b3, out, n);
    } else if (ws_size >= (size_t)WS_TBL_NEED) {
        conv_tables<<<dim3(4096), dim3(256), 0, stream>>>(tables, W1, W2, W3, tbl_bf, wbf);
        hashgrid_mlp<true><<<dim3(n / 256), dim3(256), 0, stream>>>(
            ipos, tables, tbl_bf, wbf, W1, W2, W3, b1, b2, b3, out, ra);
    } else {
        hashgrid_mlp<false><<<dim3(n / 256), dim3(256), 0, stream>>>(
            ipos, tables, tbl_bf, wbf, W1, W2, W3, b1, b2, b3, out, ra);
    }
}

// Round 11
// 629.004 us; speedup vs baseline: 2.1118x; 1.1024x over previous
//
#include <hip/hip_runtime.h>
#include <cmath>

typedef __attribute__((ext_vector_type(8))) short bf16x8;
typedef __attribute__((ext_vector_type(4))) float f32x4;
typedef __attribute__((ext_vector_type(2))) float f32x2;

#define TBLSZ (1 << 18)
#define TMASK (TBLSZ - 1)
#define N_ENTRIES ((long long)16 * TBLSZ)
#define FP8_SCALE 8192.0f
#define FP8_INV   (1.0f / 8192.0f)
// ws layout: [tbl8: 4M x 4B = 16MB][wbf: 9216 bf16 (pad 32KB)][feats_lm: 16 x 1M x 8B = 128MB]
#define WS_TBL_BYTES (N_ENTRIES * 4)
#define WS_W_BYTES   (32 * 1024)
#define WS_TBL_NEED  (WS_TBL_BYTES + WS_W_BYTES)
#define WS_FEAT_BYTES ((long long)(1 << 20) * 128)
#define WS_FULL_NEED (WS_TBL_NEED + WS_FEAT_BYTES)

struct ResArgs { float r[16]; };

__device__ __forceinline__ unsigned short f2bf(float f) {
    unsigned u = __float_as_uint(f);
    u += 0x7fffu + ((u >> 16) & 1u);   // RTNE
    return (unsigned short)(u >> 16);
}

// ---- one hash-grid level, fp8 tables (scaled 2^13): returns packed {f0|f1, f2|f3} bf16 ----
__device__ __forceinline__ uint2 enc_level_fp8(const unsigned* __restrict__ tbl,
                                               float px, float py, float pz, float res) {
    float xl = px * res, yl = py * res, zl = pz * res;
    float fx = floorf(xl), fy = floorf(yl), fz = floorf(zl);
    float tx = xl - fx, ty = yl - fy, tz = zl - fz;
    unsigned cx = (unsigned)(int)fx, cy = (unsigned)(int)fy, cz = (unsigned)(int)fz;
    unsigned hx[2] = { cx, cx + 1u };
    unsigned hy[2] = { cy * 2654435761u, cy * 2654435761u + 2654435761u };
    unsigned hz[2] = { cz * 805459861u,  cz * 805459861u + 805459861u };
    float wx[2] = { 1.f - tx, tx }, wy[2] = { 1.f - ty, ty }, wz[2] = { 1.f - tz, tz };
    float a0 = 0.f, a1 = 0.f, a2 = 0.f, a3 = 0.f;
    #pragma unroll
    for (int c = 0; c < 8; ++c) {
        const int ox = (c >> 2) & 1, oy = (c >> 1) & 1, oz = c & 1;
        unsigned h = (hx[ox] ^ hy[oy] ^ hz[oz]) & TMASK;
        unsigned v = tbl[h];
        float ww = wx[ox] * wy[oy] * wz[oz];
        f32x2 lo = __builtin_amdgcn_cvt_pk_f32_fp8(v, false);
        f32x2 hi = __builtin_amdgcn_cvt_pk_f32_fp8(v, true);
        a0 = fmaf(ww, lo[0], a0); a1 = fmaf(ww, lo[1], a1);
        a2 = fmaf(ww, hi[0], a2); a3 = fmaf(ww, hi[1], a3);
    }
    a0 *= FP8_INV; a1 *= FP8_INV; a2 *= FP8_INV; a3 *= FP8_INV;
    uint2 pk;
    pk.x = (unsigned)f2bf(a0) | ((unsigned)f2bf(a1) << 16);
    pk.y = (unsigned)f2bf(a2) | ((unsigned)f2bf(a3) << 16);
    return pk;
}

__device__ __forceinline__ uint2 enc_level_f32(const float4* __restrict__ tbl,
                                               float px, float py, float pz, float res) {
    float xl = px * res, yl = py * res, zl = pz * res;
    float fx = floorf(xl), fy = floorf(yl), fz = floorf(zl);
    float tx = xl - fx, ty = yl - fy, tz = zl - fz;
    unsigned cx = (unsigned)(int)fx, cy = (unsigned)(int)fy, cz = (unsigned)(int)fz;
    unsigned hx[2] = { cx, cx + 1u };
    unsigned hy[2] = { cy * 2654435761u, cy * 2654435761u + 2654435761u };
    unsigned hz[2] = { cz * 805459861u,  cz * 805459861u + 805459861u };
    float wx[2] = { 1.f - tx, tx }, wy[2] = { 1.f - ty, ty }, wz[2] = { 1.f - tz, tz };
    float a0 = 0.f, a1 = 0.f, a2 = 0.f, a3 = 0.f;
    #pragma unroll
    for (int c = 0; c < 8; ++c) {
        const int ox = (c >> 2) & 1, oy = (c >> 1) & 1, oz = c & 1;
        unsigned h = (hx[ox] ^ hy[oy] ^ hz[oz]) & TMASK;
        float4 v = tbl[h];
        float ww = wx[ox] * wy[oy] * wz[oz];
        a0 = fmaf(ww, v.x, a0); a1 = fmaf(ww, v.y, a1);
        a2 = fmaf(ww, v.z, a2); a3 = fmaf(ww, v.w, a3);
    }
    uint2 pk;
    pk.x = (unsigned)f2bf(a0) | ((unsigned)f2bf(a1) << 16);
    pk.y = (unsigned)f2bf(a2) | ((unsigned)f2bf(a3) << 16);
    return pk;
}

// ---- prologue: f32 tables -> fp8 (x8192), weights -> bf16, in ws ----
__global__ __launch_bounds__(256) void conv_tables(
    const float4* __restrict__ tables,
    const float* __restrict__ W1, const float* __restrict__ W2,
    const float* __restrict__ W3,
    unsigned* __restrict__ tbl8, unsigned short* __restrict__ wbf)
{
    const int t = threadIdx.x;
    for (long long i = (long long)blockIdx.x * 256 + t; i < N_ENTRIES;
         i += (long long)gridDim.x * 256) {
        float4 v = tables[i];
        int p = 0;
        p = __builtin_amdgcn_cvt_pk_fp8_f32(v.x * FP8_SCALE, v.y * FP8_SCALE, p, false);
        p = __builtin_amdgcn_cvt_pk_fp8_f32(v.z * FP8_SCALE, v.w * FP8_SCALE, p, true);
        tbl8[i] = (unsigned)p;
    }
    if (blockIdx.x == 0) {
        const int base = t * 16;
        #pragma unroll
        for (int e = 0; e < 16; ++e) wbf[base + e] = f2bf(W1[base + e]);
        #pragma unroll
        for (int e = 0; e < 16; ++e) wbf[4096 + base + e] = f2bf(W2[base + e]);
        if (t < 32) {
            #pragma unroll
            for (int e = 0; e < 16; ++e) wbf[8192 + base + e] = f2bf(W3[base + e]);
        } else if (t < 64) {
            #pragma unroll
            for (int e = 0; e < 16; ++e) wbf[8192 + base + e] = 0;
        }
    }
}

// ---- phase 1: LEVEL-MAJOR encode, fp8 tables. One block = one level x 256 points. ----
__global__ __launch_bounds__(256) void encode_lm(
    const float* __restrict__ ipos,
    const unsigned* __restrict__ tbl8,
    uint2* __restrict__ feats_lm,        // [16][npts] uint2 (4 bf16 feats)
    int chunks, int npts, ResArgs ra)
{
    const unsigned bid = blockIdx.x;
    const int lvl   = bid / (unsigned)chunks;
    const int chunk = bid - lvl * chunks;
    const long long pt = (long long)chunk * 256 + threadIdx.x;
    const float px = ipos[pt * 3 + 0];
    const float py = ipos[pt * 3 + 1];
    const float pz = ipos[pt * 3 + 2];
    uint2 pk = enc_level_fp8(tbl8 + (size_t)lvl * TBLSZ, px, py, pz, ra.r[lvl]);
    feats_lm[(size_t)lvl * npts + pt] = pk;   // coalesced 8B store
}

// ---- phase 2: MLP via MFMA; gather 16 levels per point (coalesced), LDS transpose ----
__global__ __launch_bounds__(256, 4) void mlp_lm(
    const uint2* __restrict__ feats_lm,
    const unsigned short* __restrict__ wbf,
    const float* __restrict__ b1, const float* __restrict__ b2,
    const float* __restrict__ b3,
    float* __restrict__ out, int npts)
{
    __shared__ __attribute__((aligned(16))) unsigned short xb[4][8][64][8];
    const int t   = threadIdx.x;
    const int w   = t >> 6;
    const int l   = t & 63;
    const int q   = l >> 4;
    const int l16 = l & 15;
    const long long gi = (long long)blockIdx.x * 256 + t;
    const int n2base = (l >> 4) * 2;

    #pragma unroll
    for (int lvl = 0; lvl < 16; ++lvl) {
        uint2 pk = feats_lm[(size_t)lvl * npts + gi];
        const int blk = n2base + (lvl >> 3);
        const int lp  = l16 + 16 * ((lvl & 7) >> 1);
        *(uint2*)&xb[w][blk][lp][(lvl & 1) * 4] = pk;
    }
    // no barrier: each wave reads only its own xb[w] blocks (DS in-order per wave)

    #pragma unroll 1
    for (int layer = 0; layer < 2; ++layer) {
        const float* bptr = layer ? b2 : b1;
        const unsigned short* wp = wbf + layer * 4096;
        f32x4 acc[4][4];
        #pragma unroll
        for (int m = 0; m < 4; ++m) {
            bf16x8 af0 = *(const bf16x8*)(wp + (m * 16 + l16) * 64 +  0 + q * 8);
            bf16x8 af1 = *(const bf16x8*)(wp + (m * 16 + l16) * 64 + 32 + q * 8);
            #pragma unroll
            for (int n = 0; n < 4; ++n) {
                f32x4 d = { 0.f, 0.f, 0.f, 0.f };
                d = __builtin_amdgcn_mfma_f32_16x16x32_bf16(af0, *(const bf16x8*)&xb[w][n * 2 + 0][l][0], d, 0, 0, 0);
                d = __builtin_amdgcn_mfma_f32_16x16x32_bf16(af1, *(const bf16x8*)&xb[w][n * 2 + 1][l][0], d, 0, 0, 0);
                acc[m][n] = d;
            }
        }
        #pragma unroll
        for (int m = 0; m < 4; ++m) {
            #pragma unroll
            for (int n = 0; n < 4; ++n) {
                #pragma unroll
                for (int rr = 0; rr < 4; rr += 2) {
                    const int j0 = m * 16 + q * 4 + rr;
                    float v0 = fmaxf(acc[m][n][rr]     + bptr[j0],     0.f);
                    float v1 = fmaxf(acc[m][n][rr + 1] + bptr[j0 + 1], 0.f);
                    unsigned pk = (unsigned)f2bf(v0) | ((unsigned)f2bf(v1) << 16);
                    const int blk = n * 2 + (j0 >> 5);
                    const int lp  = l16 + 16 * ((j0 & 31) >> 3);
                    *(unsigned*)&xb[w][blk][lp][j0 & 7] = pk;
                }
            }
        }
    }

    // layer 3 + sigmoid, coalesced f32x4 stores
    {
        bf16x8 af0 = *(const bf16x8*)(wbf + 8192 + l16 * 64 +  0 + q * 8);
        bf16x8 af1 = *(const bf16x8*)(wbf + 8192 + l16 * 64 + 32 + q * 8);
        const long long gbase = (long long)blockIdx.x * 256 + w * 64;
        #pragma unroll
        for (int n = 0; n < 4; ++n) {
            f32x4 d = { 0.f, 0.f, 0.f, 0.f };
            d = __builtin_amdgcn_mfma_f32_16x16x32_bf16(af0, *(const bf16x8*)&xb[w][n * 2 + 0][l][0], d, 0, 0, 0);
            d = __builtin_amdgcn_mfma_f32_16x16x32_bf16(af1, *(const bf16x8*)&xb[w][n * 2 + 1][l][0], d, 0, 0, 0);
            if (q < 2) {
                f32x4 o;
                #pragma unroll
                for (int r = 0; r < 4; ++r) {
                    float v = d[r] + b3[q * 4 + r];
                    o[r] = 1.f / (1.f + __expf(-v));
                }
                *(f32x4*)&out[(gbase + n * 16 + l16) * 8 + q * 4] = o;
            }
        }
    }
}

// ---- fallback: fused kernel, FP8 via ws or pure f32 ----
template<bool BF>
__global__ __launch_bounds__(256, 4) void hashgrid_mlp(
    const float* __restrict__ ipos,
    const float4* __restrict__ tables_f32,
    const unsigned* __restrict__ tbl8,
    const unsigned short* __restrict__ wbf,
    const float* __restrict__ W1, const float* __restrict__ W2,
    const float* __restrict__ W3,
    const float* __restrict__ b1, const float* __restrict__ b2,
    const float* __restrict__ b3,
    float* __restrict__ out, ResArgs ra)
{
    __shared__ __attribute__((aligned(16))) unsigned short xb[4][8][64][8];
    const int t   = threadIdx.x;
    const int w   = t >> 6;
    const int l   = t & 63;
    const int q   = l >> 4;
    const int l16 = l & 15;

    {
        const long long gi = (long long)blockIdx.x * 256 + t;
        const float px = ipos[gi * 3 + 0];
        const float py = ipos[gi * 3 + 1];
        const float pz = ipos[gi * 3 + 2];
        const int n2base = (l >> 4) * 2;
        #pragma unroll 2
        for (int lvl = 0; lvl < 16; ++lvl) {
            uint2 pk = BF ? enc_level_fp8(tbl8 + (size_t)lvl * TBLSZ, px, py, pz, ra.r[lvl])
                          : enc_level_f32(tables_f32 + (size_t)lvl * TBLSZ, px, py, pz, ra.r[lvl]);
            const int blk = n2base + (lvl >> 3);
            const int lp  = l16 + 16 * ((lvl & 7) >> 1);
            *(uint2*)&xb[w][blk][lp][(lvl & 1) * 4] = pk;
        }
    }

    #pragma unroll 1
    for (int layer = 0; layer < 2; ++layer) {
        const float* bptr = layer ? b2 : b1;
        f32x4 acc[4][4];
        #pragma unroll
        for (int m = 0; m < 4; ++m) {
            bf16x8 af0, af1;
            if constexpr (BF) {
                const unsigned short* wp = wbf + layer * 4096;
                af0 = *(const bf16x8*)(wp + (m * 16 + l16) * 64 +  0 + q * 8);
                af1 = *(const bf16x8*)(wp + (m * 16 + l16) * 64 + 32 + q * 8);
            } else {
                const float* Wp = layer ? W2 : W1;
                const float* r0 = Wp + (m * 16 + l16) * 64 + q * 8;
                float4 a = *(const float4*)(r0), b = *(const float4*)(r0 + 4);
                float4 c = *(const float4*)(r0 + 32), e = *(const float4*)(r0 + 36);
                af0[0]=f2bf(a.x);af0[1]=f2bf(a.y);af0[2]=f2bf(a.z);af0[3]=f2bf(a.w);
                af0[4]=f2bf(b.x);af0[5]=f2bf(b.y);af0[6]=f2bf(b.z);af0[7]=f2bf(b.w);
                af1[0]=f2bf(c.x);af1[1]=f2bf(c.y);af1[2]=f2bf(c.z);af1[3]=f2bf(c.w);
                af1[4]=f2bf(e.x);af1[5]=f2bf(e.y);af1[6]=f2bf(e.z);af1[7]=f2bf(e.w);
            }
            #pragma unroll
            for (int n = 0; n < 4; ++n) {
                f32x4 d = { 0.f, 0.f, 0.f, 0.f };
                d = __builtin_amdgcn_mfma_f32_16x16x32_bf16(af0, *(const bf16x8*)&xb[w][n * 2 + 0][l][0], d, 0, 0, 0);
                d = __builtin_amdgcn_mfma_f32_16x16x32_bf16(af1, *(const bf16x8*)&xb[w][n * 2 + 1][l][0], d, 0, 0, 0);
                acc[m][n] = d;
            }
        }
        #pragma unroll
        for (int m = 0; m < 4; ++m) {
            #pragma unroll
            for (int n = 0; n < 4; ++n) {
                #pragma unroll
                for (int rr = 0; rr < 4; rr += 2) {
                    const int j0 = m * 16 + q * 4 + rr;
                    float v0 = fmaxf(acc[m][n][rr]     + bptr[j0],     0.f);
                    float v1 = fmaxf(acc[m][n][rr + 1] + bptr[j0 + 1], 0.f);
                    unsigned pk = (unsigned)f2bf(v0) | ((unsigned)f2bf(v1) << 16);
                    const int blk = n * 2 + (j0 >> 5);
                    const int lp  = l16 + 16 * ((j0 & 31) >> 3);
                    *(unsigned*)&xb[w][blk][lp][j0 & 7] = pk;
                }
            }
        }
    }

    {
        bf16x8 af0, af1;
        if constexpr (BF) {
            af0 = *(const bf16x8*)(wbf + 8192 + l16 * 64 +  0 + q * 8);
            af1 = *(const bf16x8*)(wbf + 8192 + l16 * 64 + 32 + q * 8);
        } else {
            if (l16 < 8) {
                const float* r0 = W3 + l16 * 64 + q * 8;
                float4 a = *(const float4*)(r0), b = *(const float4*)(r0 + 4);
                float4 c = *(const float4*)(r0 + 32), e = *(const float4*)(r0 + 36);
                af0[0]=f2bf(a.x);af0[1]=f2bf(a.y);af0[2]=f2bf(a.z);af0[3]=f2bf(a.w);
                af0[4]=f2bf(b.x);af0[5]=f2bf(b.y);af0[6]=f2bf(b.z);af0[7]=f2bf(b.w);
                af1[0]=f2bf(c.x);af1[1]=f2bf(c.y);af1[2]=f2bf(c.z);af1[3]=f2bf(c.w);
                af1[4]=f2bf(e.x);af1[5]=f2bf(e.y);af1[6]=f2bf(e.z);af1[7]=f2bf(e.w);
            } else {
                af0 = bf16x8{0,0,0,0,0,0,0,0};
                af1 = bf16x8{0,0,0,0,0,0,0,0};
            }
        }
        const long long gbase = (long long)blockIdx.x * 256 + w * 64;
        #pragma unroll
        for (int n = 0; n < 4; ++n) {
            f32x4 d = { 0.f, 0.f, 0.f, 0.f };
            d = __builtin_amdgcn_mfma_f32_16x16x32_bf16(af0, *(const bf16x8*)&xb[w][n * 2 + 0][l][0], d, 0, 0, 0);
            d = __builtin_amdgcn_mfma_f32_16x16x32_bf16(af1, *(const bf16x8*)&xb[w][n * 2 + 1][l][0], d, 0, 0, 0);
            if (q < 2) {
                f32x4 o;
                #pragma unroll
                for (int r = 0; r < 4; ++r) {
                    float v = d[r] + b3[q * 4 + r];
                    o[r] = 1.f / (1.f + __expf(-v));
                }
                *(f32x4*)&out[(gbase + n * 16 + l16) * 8 + q * 4] = o;
            }
        }
    }
}

extern "C" void kernel_launch(void* const* d_in, const int* in_sizes, int n_in,
                              void* d_out, int out_size, void* d_ws, size_t ws_size,
                              hipStream_t stream) {
    const float*  ipos   = (const float*)d_in[0];
    const float4* tables = (const float4*)d_in[1];
    const float*  W1 = (const float*)d_in[2];
    const float*  b1 = (const float*)d_in[3];
    const float*  W2 = (const float*)d_in[4];
    const float*  b2 = (const float*)d_in[5];
    const float*  W3 = (const float*)d_in[6];
    const float*  b3 = (const float*)d_in[7];
    float* out = (float*)d_out;

    ResArgs ra;
    const double g = exp((log(512.0) - log(16.0)) / 15.0);   // matches Python libm
    for (int lvl = 0; lvl < 16; ++lvl)
        ra.r[lvl] = (float)floor(16.0 * pow(g, (double)lvl));

    const int n = in_sizes[0] / 3;           // 1<<20

    unsigned* tbl8 = (unsigned*)d_ws;
    unsigned short* wbf = (unsigned short*)((char*)d_ws + WS_TBL_BYTES);
    uint2* feats_lm = (uint2*)((char*)d_ws + WS_TBL_NEED);

    if (ws_size >= (size_t)WS_FULL_NEED) {   // ws_size constant per harness -> deterministic
        const int chunks = n / 256;          // 4096
        conv_tables<<<dim3(4096), dim3(256), 0, stream>>>(tables, W1, W2, W3, tbl8, wbf);
        encode_lm<<<dim3(16 * chunks), dim3(256), 0, stream>>>(ipos, tbl8, feats_lm, chunks, n, ra);
        mlp_lm<<<dim3(chunks), dim3(256), 0, stream>>>(feats_lm, wbf, b1, b2, b3, out, n);
    } else if (ws_size >= (size_t)WS_TBL_NEED) {
        conv_tables<<<dim3(4096), dim3(256), 0, stream>>>(tables, W1, W2, W3, tbl8, wbf);
        hashgrid_mlp<true><<<dim3(n / 256), dim3(256), 0, stream>>>(
            ipos, tables, tbl8, wbf, W1, W2, W3, b1, b2, b3, out, ra);
    } else {
        hashgrid_mlp<false><<<dim3(n / 256), dim3(256), 0, stream>>>(
            ipos, tables, tbl8, wbf, W1, W2, W3, b1, b2, b3, out, ra);
    }
}

// Round 13
// 481.866 us; speedup vs baseline: 2.7567x; 1.3054x over previous
//
#include <hip/hip_runtime.h>
#include <cmath>

typedef __attribute__((ext_vector_type(8))) short bf16x8;
typedef __attribute__((ext_vector_type(4))) float f32x4;
typedef __attribute__((ext_vector_type(2))) float f32x2;

#define TBLSZ (1 << 18)
#define TMASK (TBLSZ - 1)
#define N_ENTRIES ((long long)16 * TBLSZ)
#define FP8_SCALE 8192.0f
#define FP8_INV   (1.0f / 8192.0f)
#define P2 2654435761u
#define P3 805459861u
#define N_DENSE 8
// ws layout: [tbl8 16MB][wbf 64KB][dense blocks ~33MB][feats8 64MB]
#define WS_TBL_BYTES (N_ENTRIES * 4)
#define WS_W_BYTES   (64 * 1024)
#define WS_TBL_NEED  (WS_TBL_BYTES + WS_W_BYTES)

struct ResArgs { float r[16]; };
struct EncArgs { float r[16]; int doff[16]; };   // doff: dword offset into dense, -1 = hashed

__device__ __forceinline__ unsigned short f2bf(float f) {
    unsigned u = __float_as_uint(f);
    u += 0x7fffu + ((u >> 16) & 1u);   // RTNE
    return (unsigned short)(u >> 16);
}

// ---- hashed level, fp8 tables, x-pair merged loads; returns fp8x4 (scaled) ----
__device__ __forceinline__ unsigned enc_level_hash8(const unsigned* __restrict__ tbl,
                                                    float px, float py, float pz, float res) {
    float xl = px * res, yl = py * res, zl = pz * res;
    float fx = floorf(xl), fy = floorf(yl), fz = floorf(zl);
    float tx = xl - fx, ty = yl - fy, tz = zl - fz;
    unsigned cx = (unsigned)(int)fx, cy = (unsigned)(int)fy, cz = (unsigned)(int)fz;
    unsigned hy2[2] = { cy * P2, cy * P2 + P2 };
    unsigned hz2[2] = { cz * P3, cz * P3 + P3 };
    float wx[2] = { 1.f - tx, tx }, wy[2] = { 1.f - ty, ty }, wz[2] = { 1.f - tz, tz };
    const bool codd = (cx & 1u) != 0u;
    unsigned ss[4], v0s[4], v1s[4];
    #pragma unroll
    for (int c = 0; c < 4; ++c) {              // c = oy*2+oz
        const int oy = (c >> 1) & 1, oz = c & 1;
        unsigned s = hy2[oy] ^ hz2[oz];
        ss[c] = s;
        unsigned h0 = (cx ^ s) & TMASK;
        uint2 pr = *(const uint2*)(tbl + (h0 & ~1u));   // aligned 8B pair
        v0s[c] = (h0 & 1u) ? pr.y : pr.x;
        v1s[c] = (h0 & 1u) ? pr.x : pr.y;               // valid when cx even (h1 = h0^1)
    }
    if (codd) {                                 // one divergent region, 4 masked loads
        #pragma unroll
        for (int c = 0; c < 4; ++c)
            v1s[c] = tbl[((cx + 1u) ^ ss[c]) & TMASK];
    }
    float a0 = 0.f, a1 = 0.f, a2 = 0.f, a3 = 0.f;
    #pragma unroll
    for (int c = 0; c < 4; ++c) {
        const int oy = (c >> 1) & 1, oz = c & 1;
        float w0 = wx[0] * wy[oy] * wz[oz];
        float w1 = wx[1] * wy[oy] * wz[oz];
        f32x2 lo0 = __builtin_amdgcn_cvt_pk_f32_fp8(v0s[c], false);
        f32x2 hi0 = __builtin_amdgcn_cvt_pk_f32_fp8(v0s[c], true);
        a0 = fmaf(w0, lo0[0], a0); a1 = fmaf(w0, lo0[1], a1);
        a2 = fmaf(w0, hi0[0], a2); a3 = fmaf(w0, hi0[1], a3);
        f32x2 lo1 = __builtin_amdgcn_cvt_pk_f32_fp8(v1s[c], false);
        f32x2 hi1 = __builtin_amdgcn_cvt_pk_f32_fp8(v1s[c], true);
        a0 = fmaf(w1, lo1[0], a0); a1 = fmaf(w1, lo1[1], a1);
        a2 = fmaf(w1, hi1[0], a2); a3 = fmaf(w1, hi1[1], a3);
    }
    int p = 0;
    p = __builtin_amdgcn_cvt_pk_fp8_f32(a0, a1, p, false);
    p = __builtin_amdgcn_cvt_pk_fp8_f32(a2, a3, p, true);
    return (unsigned)p;
}

// ---- dense level: one 32B block per cell holds all 8 corners; 2 requests/point ----
__device__ __forceinline__ unsigned enc_level_dense(const unsigned* __restrict__ blk,
                                                    int resi, float px, float py, float pz, float res) {
    float xl = px * res, yl = py * res, zl = pz * res;
    float fx = floorf(xl), fy = floorf(yl), fz = floorf(zl);
    float tx = xl - fx, ty = yl - fy, tz = zl - fz;
    int cx = (int)fx, cy = (int)fy, cz = (int)fz;
    long long cell = ((long long)cx * resi + cy) * resi + cz;
    const uint4* bp = (const uint4*)(blk + cell * 8);
    uint4 A = bp[0], B = bp[1];
    float wx[2] = { 1.f - tx, tx }, wy[2] = { 1.f - ty, ty }, wz[2] = { 1.f - tz, tz };
    unsigned vs[8] = { A.x, A.y, A.z, A.w, B.x, B.y, B.z, B.w };
    float a0 = 0.f, a1 = 0.f, a2 = 0.f, a3 = 0.f;
    #pragma unroll
    for (int c = 0; c < 8; ++c) {              // c = ox*4+oy*2+oz (matches build)
        float ww = wx[(c >> 2) & 1] * wy[(c >> 1) & 1] * wz[c & 1];
        f32x2 lo = __builtin_amdgcn_cvt_pk_f32_fp8(vs[c], false);
        f32x2 hi = __builtin_amdgcn_cvt_pk_f32_fp8(vs[c], true);
        a0 = fmaf(ww, lo[0], a0); a1 = fmaf(ww, lo[1], a1);
        a2 = fmaf(ww, hi[0], a2); a3 = fmaf(ww, hi[1], a3);
    }
    int p = 0;
    p = __builtin_amdgcn_cvt_pk_fp8_f32(a0, a1, p, false);
    p = __builtin_amdgcn_cvt_pk_fp8_f32(a2, a3, p, true);
    return (unsigned)p;
}

// ---- fallback helpers (bf16 feat output) ----
__device__ __forceinline__ uint2 enc_level_fp8(const unsigned* __restrict__ tbl,
                                               float px, float py, float pz, float res) {
    float xl = px * res, yl = py * res, zl = pz * res;
    float fx = floorf(xl), fy = floorf(yl), fz = floorf(zl);
    float tx = xl - fx, ty = yl - fy, tz = zl - fz;
    unsigned cx = (unsigned)(int)fx, cy = (unsigned)(int)fy, cz = (unsigned)(int)fz;
    unsigned hx[2] = { cx, cx + 1u };
    unsigned hy[2] = { cy * P2, cy * P2 + P2 };
    unsigned hz[2] = { cz * P3, cz * P3 + P3 };
    float wx[2] = { 1.f - tx, tx }, wy[2] = { 1.f - ty, ty }, wz[2] = { 1.f - tz, tz };
    float a0 = 0.f, a1 = 0.f, a2 = 0.f, a3 = 0.f;
    #pragma unroll
    for (int c = 0; c < 8; ++c) {
        const int ox = (c >> 2) & 1, oy = (c >> 1) & 1, oz = c & 1;
        unsigned h = (hx[ox] ^ hy[oy] ^ hz[oz]) & TMASK;
        unsigned v = tbl[h];
        float ww = wx[ox] * wy[oy] * wz[oz];
        f32x2 lo = __builtin_amdgcn_cvt_pk_f32_fp8(v, false);
        f32x2 hi = __builtin_amdgcn_cvt_pk_f32_fp8(v, true);
        a0 = fmaf(ww, lo[0], a0); a1 = fmaf(ww, lo[1], a1);
        a2 = fmaf(ww, hi[0], a2); a3 = fmaf(ww, hi[1], a3);
    }
    a0 *= FP8_INV; a1 *= FP8_INV; a2 *= FP8_INV; a3 *= FP8_INV;
    uint2 pk;
    pk.x = (unsigned)f2bf(a0) | ((unsigned)f2bf(a1) << 16);
    pk.y = (unsigned)f2bf(a2) | ((unsigned)f2bf(a3) << 16);
    return pk;
}

__device__ __forceinline__ uint2 enc_level_f32(const float4* __restrict__ tbl,
                                               float px, float py, float pz, float res) {
    float xl = px * res, yl = py * res, zl = pz * res;
    float fx = floorf(xl), fy = floorf(yl), fz = floorf(zl);
    float tx = xl - fx, ty = yl - fy, tz = zl - fz;
    unsigned cx = (unsigned)(int)fx, cy = (unsigned)(int)fy, cz = (unsigned)(int)fz;
    unsigned hx[2] = { cx, cx + 1u };
    unsigned hy[2] = { cy * P2, cy * P2 + P2 };
    unsigned hz[2] = { cz * P3, cz * P3 + P3 };
    float wx[2] = { 1.f - tx, tx }, wy[2] = { 1.f - ty, ty }, wz[2] = { 1.f - tz, tz };
    float a0 = 0.f, a1 = 0.f, a2 = 0.f, a3 = 0.f;
    #pragma unroll
    for (int c = 0; c < 8; ++c) {
        const int ox = (c >> 2) & 1, oy = (c >> 1) & 1, oz = c & 1;
        unsigned h = (hx[ox] ^ hy[oy] ^ hz[oz]) & TMASK;
        float4 v = tbl[h];
        float ww = wx[ox] * wy[oy] * wz[oz];
        a0 = fmaf(ww, v.x, a0); a1 = fmaf(ww, v.y, a1);
        a2 = fmaf(ww, v.z, a2); a3 = fmaf(ww, v.w, a3);
    }
    uint2 pk;
    pk.x = (unsigned)f2bf(a0) | ((unsigned)f2bf(a1) << 16);
    pk.y = (unsigned)f2bf(a2) | ((unsigned)f2bf(a3) << 16);
    return pk;
}

// ---- prologue 1: f32 tables -> fp8 (x8192), weights -> bf16 ----
__global__ __launch_bounds__(256) void conv_tables(
    const float4* __restrict__ tables,
    const float* __restrict__ W1, const float* __restrict__ W2,
    const float* __restrict__ W3,
    unsigned* __restrict__ tbl8, unsigned short* __restrict__ wbf)
{
    const int t = threadIdx.x;
    for (long long i = (long long)blockIdx.x * 256 + t; i < N_ENTRIES;
         i += (long long)gridDim.x * 256) {
        float4 v = tables[i];
        int p = 0;
        p = __builtin_amdgcn_cvt_pk_fp8_f32(v.x * FP8_SCALE, v.y * FP8_SCALE, p, false);
        p = __builtin_amdgcn_cvt_pk_fp8_f32(v.z * FP8_SCALE, v.w * FP8_SCALE, p, true);
        tbl8[i] = (unsigned)p;
    }
    if (blockIdx.x == 0) {
        const int base = t * 16;
        #pragma unroll
        for (int e = 0; e < 16; ++e) wbf[base + e] = f2bf(W1[base + e]);
        #pragma unroll
        for (int e = 0; e < 16; ++e) wbf[4096 + base + e] = f2bf(W2[base + e]);
        if (t < 32) {
            #pragma unroll
            for (int e = 0; e < 16; ++e) wbf[8192 + base + e] = f2bf(W3[base + e]);
        } else if (t < 64) {
            #pragma unroll
            for (int e = 0; e < 16; ++e) wbf[8192 + base + e] = 0;
        }
    }
}

// ---- prologue 2 (per dense level): gather 8 corners of each cell into one 32B block ----
__global__ __launch_bounds__(256) void build_dense(
    const unsigned* __restrict__ tbl, unsigned* __restrict__ blk, int resi, int ncells)
{
    int i = blockIdx.x * 256 + threadIdx.x;
    if (i >= ncells) return;
    int cz = i % resi; int r = i / resi; int cy = r % resi; int cx = r / resi;
    unsigned o[8];
    #pragma unroll
    for (int c = 0; c < 8; ++c) {              // c = ox*4+oy*2+oz
        unsigned hx = (unsigned)(cx + ((c >> 2) & 1));
        unsigned hy = (unsigned)(cy + ((c >> 1) & 1)) * P2;
        unsigned hz = (unsigned)(cz + (c & 1)) * P3;
        o[c] = tbl[(hx ^ hy ^ hz) & TMASK];
    }
    uint4* bp = (uint4*)(blk + (size_t)i * 8);
    uint4 A; A.x = o[0]; A.y = o[1]; A.z = o[2]; A.w = o[3];
    uint4 B; B.x = o[4]; B.y = o[5]; B.z = o[6]; B.w = o[7];
    bp[0] = A; bp[1] = B;
}

// ---- phase 1: level-major encode; dense path for l<8, hashed+x-pair for l>=8 ----
__global__ __launch_bounds__(256) void encode_lm(
    const float* __restrict__ ipos,
    const unsigned* __restrict__ tbl8,
    const unsigned* __restrict__ dense,
    unsigned* __restrict__ feats8,       // [16][npts] fp8x4 (scaled 2^13)
    int chunks, int npts, EncArgs ea)
{
    const unsigned bid = blockIdx.x;
    const int lvl   = bid / (unsigned)chunks;
    const int chunk = bid - lvl * chunks;
    const long long pt = (long long)chunk * 256 + threadIdx.x;
    const float px = ipos[pt * 3 + 0];
    const float py = ipos[pt * 3 + 1];
    const float pz = ipos[pt * 3 + 2];
    const int doff = ea.doff[lvl];
    unsigned pk;
    if (doff >= 0)
        pk = enc_level_dense(dense + doff, (int)ea.r[lvl], px, py, pz, ea.r[lvl]);
    else
        pk = enc_level_hash8(tbl8 + (size_t)lvl * TBLSZ, px, py, pz, ea.r[lvl]);
    feats8[(size_t)lvl * npts + pt] = pk;    // coalesced 4B store
}

// ---- phase 2: MLP via MFMA; fp8 feats -> bf16 B-frags via LDS transpose ----
__global__ __launch_bounds__(256, 4) void mlp_lm(
    const unsigned* __restrict__ feats8,
    const unsigned short* __restrict__ wbf,
    const float* __restrict__ b1, const float* __restrict__ b2,
    const float* __restrict__ b3,
    float* __restrict__ out, int npts)
{
    __shared__ __attribute__((aligned(16))) unsigned short xb[4][8][64][8];
    const int t   = threadIdx.x;
    const int w   = t >> 6;
    const int l   = t & 63;
    const int q   = l >> 4;
    const int l16 = l & 15;
    const long long gi = (long long)blockIdx.x * 256 + t;
    const int n2base = (l >> 4) * 2;

    #pragma unroll
    for (int lvl = 0; lvl < 16; ++lvl) {
        unsigned v = feats8[(size_t)lvl * npts + gi];
        f32x2 lo = __builtin_amdgcn_cvt_pk_f32_fp8(v, false);
        f32x2 hi = __builtin_amdgcn_cvt_pk_f32_fp8(v, true);
        uint2 pk;
        pk.x = (unsigned)f2bf(lo[0] * FP8_INV) | ((unsigned)f2bf(lo[1] * FP8_INV) << 16);
        pk.y = (unsigned)f2bf(hi[0] * FP8_INV) | ((unsigned)f2bf(hi[1] * FP8_INV) << 16);
        const int blk = n2base + (lvl >> 3);
        const int lp  = l16 + 16 * ((lvl & 7) >> 1);
        *(uint2*)&xb[w][blk][lp][(lvl & 1) * 4] = pk;
    }
    // no barrier: each wave reads only its own xb[w] blocks (DS in-order per wave)

    #pragma unroll 1
    for (int layer = 0; layer < 2; ++layer) {
        const float* bptr = layer ? b2 : b1;
        const unsigned short* wp = wbf + layer * 4096;
        f32x4 acc[4][4];
        #pragma unroll
        for (int m = 0; m < 4; ++m) {
            bf16x8 af0 = *(const bf16x8*)(wp + (m * 16 + l16) * 64 +  0 + q * 8);
            bf16x8 af1 = *(const bf16x8*)(wp + (m * 16 + l16) * 64 + 32 + q * 8);
            #pragma unroll
            for (int n = 0; n < 4; ++n) {
                f32x4 d = { 0.f, 0.f, 0.f, 0.f };
                d = __builtin_amdgcn_mfma_f32_16x16x32_bf16(af0, *(const bf16x8*)&xb[w][n * 2 + 0][l][0], d, 0, 0, 0);
                d = __builtin_amdgcn_mfma_f32_16x16x32_bf16(af1, *(const bf16x8*)&xb[w][n * 2 + 1][l][0], d, 0, 0, 0);
                acc[m][n] = d;
            }
        }
        #pragma unroll
        for (int m = 0; m < 4; ++m) {
            #pragma unroll
            for (int n = 0; n < 4; ++n) {
                #pragma unroll
                for (int rr = 0; rr < 4; rr += 2) {
                    const int j0 = m * 16 + q * 4 + rr;
                    float v0 = fmaxf(acc[m][n][rr]     + bptr[j0],     0.f);
                    float v1 = fmaxf(acc[m][n][rr + 1] + bptr[j0 + 1], 0.f);
                    unsigned pk = (unsigned)f2bf(v0) | ((unsigned)f2bf(v1) << 16);
                    const int blk = n * 2 + (j0 >> 5);
                    const int lp  = l16 + 16 * ((j0 & 31) >> 3);
                    *(unsigned*)&xb[w][blk][lp][j0 & 7] = pk;
                }
            }
        }
    }

    // layer 3 + sigmoid, coalesced f32x4 stores
    {
        bf16x8 af0 = *(const bf16x8*)(wbf + 8192 + l16 * 64 +  0 + q * 8);
        bf16x8 af1 = *(const bf16x8*)(wbf + 8192 + l16 * 64 + 32 + q * 8);
        const long long gbase = (long long)blockIdx.x * 256 + w * 64;
        #pragma unroll
        for (int n = 0; n < 4; ++n) {
            f32x4 d = { 0.f, 0.f, 0.f, 0.f };
            d = __builtin_amdgcn_mfma_f32_16x16x32_bf16(af0, *(const bf16x8*)&xb[w][n * 2 + 0][l][0], d, 0, 0, 0);
            d = __builtin_amdgcn_mfma_f32_16x16x32_bf16(af1, *(const bf16x8*)&xb[w][n * 2 + 1][l][0], d, 0, 0, 0);
            if (q < 2) {
                f32x4 o;
                #pragma unroll
                for (int r = 0; r < 4; ++r) {
                    float v = d[r] + b3[q * 4 + r];
                    o[r] = 1.f / (1.f + __expf(-v));
                }
                *(f32x4*)&out[(gbase + n * 16 + l16) * 8 + q * 4] = o;
            }
        }
    }
}

// ---- fallback: fused kernel, FP8 via ws or pure f32 ----
template<bool BF>
__global__ __launch_bounds__(256, 4) void hashgrid_mlp(
    const float* __restrict__ ipos,
    const float4* __restrict__ tables_f32,
    const unsigned* __restrict__ tbl8,
    const unsigned short* __restrict__ wbf,
    const float* __restrict__ W1, const float* __restrict__ W2,
    const float* __restrict__ W3,
    const float* __restrict__ b1, const float* __restrict__ b2,
    const float* __restrict__ b3,
    float* __restrict__ out, ResArgs ra)
{
    __shared__ __attribute__((aligned(16))) unsigned short xb[4][8][64][8];
    const int t   = threadIdx.x;
    const int w   = t >> 6;
    const int l   = t & 63;
    const int q   = l >> 4;
    const int l16 = l & 15;

    {
        const long long gi = (long long)blockIdx.x * 256 + t;
        const float px = ipos[gi * 3 + 0];
        const float py = ipos[gi * 3 + 1];
        const float pz = ipos[gi * 3 + 2];
        const int n2base = (l >> 4) * 2;
        #pragma unroll 2
        for (int lvl = 0; lvl < 16; ++lvl) {
            uint2 pk = BF ? enc_level_fp8(tbl8 + (size_t)lvl * TBLSZ, px, py, pz, ra.r[lvl])
                          : enc_level_f32(tables_f32 + (size_t)lvl * TBLSZ, px, py, pz, ra.r[lvl]);
            const int blk = n2base + (lvl >> 3);
            const int lp  = l16 + 16 * ((lvl & 7) >> 1);
            *(uint2*)&xb[w][blk][lp][(lvl & 1) * 4] = pk;
        }
    }

    #pragma unroll 1
    for (int layer = 0; layer < 2; ++layer) {
        const float* bptr = layer ? b2 : b1;
        f32x4 acc[4][4];
        #pragma unroll
        for (int m = 0; m < 4; ++m) {
            bf16x8 af0, af1;
            if constexpr (BF) {
                const unsigned short* wp = wbf + layer * 4096;
                af0 = *(const bf16x8*)(wp + (m * 16 + l16) * 64 +  0 + q * 8);
                af1 = *(const bf16x8*)(wp + (m * 16 + l16) * 64 + 32 + q * 8);
            } else {
                const float* Wp = layer ? W2 : W1;
                const float* r0 = Wp + (m * 16 + l16) * 64 + q * 8;
                float4 a = *(const float4*)(r0), b = *(const float4*)(r0 + 4);
                float4 c = *(const float4*)(r0 + 32), e = *(const float4*)(r0 + 36);
                af0[0]=f2bf(a.x);af0[1]=f2bf(a.y);af0[2]=f2bf(a.z);af0[3]=f2bf(a.w);
                af0[4]=f2bf(b.x);af0[5]=f2bf(b.y);af0[6]=f2bf(b.z);af0[7]=f2bf(b.w);
                af1[0]=f2bf(c.x);af1[1]=f2bf(c.y);af1[2]=f2bf(c.z);af1[3]=f2bf(c.w);
                af1[4]=f2bf(e.x);af1[5]=f2bf(e.y);af1[6]=f2bf(e.z);af1[7]=f2bf(e.w);
            }
            #pragma unroll
            for (int n = 0; n < 4; ++n) {
                f32x4 d = { 0.f, 0.f, 0.f, 0.f };
                d = __builtin_amdgcn_mfma_f32_16x16x32_bf16(af0, *(const bf16x8*)&xb[w][n * 2 + 0][l][0], d, 0, 0, 0);
                d = __builtin_amdgcn_mfma_f32_16x16x32_bf16(af1, *(const bf16x8*)&xb[w][n * 2 + 1][l][0], d, 0, 0, 0);
                acc[m][n] = d;
            }
        }
        #pragma unroll
        for (int m = 0; m < 4; ++m) {
            #pragma unroll
            for (int n = 0; n < 4; ++n) {
                #pragma unroll
                for (int rr = 0; rr < 4; rr += 2) {
                    const int j0 = m * 16 + q * 4 + rr;
                    float v0 = fmaxf(acc[m][n][rr]     + bptr[j0],     0.f);
                    float v1 = fmaxf(acc[m][n][rr + 1] + bptr[j0 + 1], 0.f);
                    unsigned pk = (unsigned)f2bf(v0) | ((unsigned)f2bf(v1) << 16);
                    const int blk = n * 2 + (j0 >> 5);
                    const int lp  = l16 + 16 * ((j0 & 31) >> 3);
                    *(unsigned*)&xb[w][blk][lp][j0 & 7] = pk;
                }
            }
        }
    }

    {
        bf16x8 af0, af1;
        if constexpr (BF) {
            af0 = *(const bf16x8*)(wbf + 8192 + l16 * 64 +  0 + q * 8);
            af1 = *(const bf16x8*)(wbf + 8192 + l16 * 64 + 32 + q * 8);
        } else {
            if (l16 < 8) {
                const float* r0 = W3 + l16 * 64 + q * 8;
                float4 a = *(const float4*)(r0), b = *(const float4*)(r0 + 4);
                float4 c = *(const float4*)(r0 + 32), e = *(const float4*)(r0 + 36);
                af0[0]=f2bf(a.x);af0[1]=f2bf(a.y);af0[2]=f2bf(a.z);af0[3]=f2bf(a.w);
                af0[4]=f2bf(b.x);af0[5]=f2bf(b.y);af0[6]=f2bf(b.z);af0[7]=f2bf(b.w);
                af1[0]=f2bf(c.x);af1[1]=f2bf(c.y);af1[2]=f2bf(c.z);af1[3]=f2bf(c.w);
                af1[4]=f2bf(e.x);af1[5]=f2bf(e.y);af1[6]=f2bf(e.z);af1[7]=f2bf(e.w);
            } else {
                af0 = bf16x8{0,0,0,0,0,0,0,0};
                af1 = bf16x8{0,0,0,0,0,0,0,0};
            }
        }
        const long long gbase = (long long)blockIdx.x * 256 + w * 64;
        #pragma unroll
        for (int n = 0; n < 4; ++n) {
            f32x4 d = { 0.f, 0.f, 0.f, 0.f };
            d = __builtin_amdgcn_mfma_f32_16x16x32_bf16(af0, *(const bf16x8*)&xb[w][n * 2 + 0][l][0], d, 0, 0, 0);
            d = __builtin_amdgcn_mfma_f32_16x16x32_bf16(af1, *(const bf16x8*)&xb[w][n * 2 + 1][l][0], d, 0, 0, 0);
            if (q < 2) {
                f32x4 o;
                #pragma unroll
                for (int r = 0; r < 4; ++r) {
                    float v = d[r] + b3[q * 4 + r];
                    o[r] = 1.f / (1.f + __expf(-v));
                }
                *(f32x4*)&out[(gbase + n * 16 + l16) * 8 + q * 4] = o;
            }
        }
    }
}

extern "C" void kernel_launch(void* const* d_in, const int* in_sizes, int n_in,
                              void* d_out, int out_size, void* d_ws, size_t ws_size,
                              hipStream_t stream) {
    const float*  ipos   = (const float*)d_in[0];
    const float4* tables = (const float4*)d_in[1];
    const float*  W1 = (const float*)d_in[2];
    const float*  b1 = (const float*)d_in[3];
    const float*  W2 = (const float*)d_in[4];
    const float*  b2 = (const float*)d_in[5];
    const float*  W3 = (const float*)d_in[6];
    const float*  b3 = (const float*)d_in[7];
    float* out = (float*)d_out;

    ResArgs ra;
    EncArgs ea;
    const double g = exp((log(512.0) - log(16.0)) / 15.0);   // matches Python libm
    int resi[16];
    for (int lvl = 0; lvl < 16; ++lvl) {
        ra.r[lvl] = (float)floor(16.0 * pow(g, (double)lvl));
        ea.r[lvl] = ra.r[lvl];
        resi[lvl] = (int)ra.r[lvl];
    }

    const int n = in_sizes[0] / 3;           // 1<<20

    unsigned char* base = (unsigned char*)d_ws;
    unsigned* tbl8 = (unsigned*)base;
    unsigned short* wbf = (unsigned short*)(base + WS_TBL_BYTES);
    unsigned* dense = (unsigned*)(base + WS_TBL_BYTES + WS_W_BYTES);

    size_t ddw = 0;                          // dense size in dwords
    int ncells[N_DENSE];
    for (int lvl = 0; lvl < 16; ++lvl) {
        if (lvl < N_DENSE) {
            ea.doff[lvl] = (int)ddw;
            long long c = (long long)resi[lvl] * resi[lvl] * resi[lvl];
            ncells[lvl] = (int)c;
            ddw += (size_t)c * 8;
        } else {
            ea.doff[lvl] = -1;
        }
    }
    unsigned* feats8 = dense + ddw;
    const size_t ws_full_need = (size_t)WS_TBL_BYTES + WS_W_BYTES + ddw * 4
                              + (size_t)n * 16 * 4;

    if (ws_size >= ws_full_need) {           // ws_size constant per harness -> deterministic
        const int chunks = n / 256;          // 4096
        conv_tables<<<dim3(4096), dim3(256), 0, stream>>>(tables, W1, W2, W3, tbl8, wbf);
        for (int lvl = 0; lvl < N_DENSE; ++lvl)
            build_dense<<<dim3((ncells[lvl] + 255) / 256), dim3(256), 0, stream>>>(
                tbl8 + (size_t)lvl * TBLSZ, dense + ea.doff[lvl], resi[lvl], ncells[lvl]);
        encode_lm<<<dim3(16 * chunks), dim3(256), 0, stream>>>(
            ipos, tbl8, dense, feats8, chunks, n, ea);
        mlp_lm<<<dim3(chunks), dim3(256), 0, stream>>>(feats8, wbf, b1, b2, b3, out, n);
    } else if (ws_size >= (size_t)WS_TBL_NEED) {
        conv_tables<<<dim3(4096), dim3(256), 0, stream>>>(tables, W1, W2, W3, tbl8, wbf);
        hashgrid_mlp<true><<<dim3(n / 256), dim3(256), 0, stream>>>(
            ipos, tables, tbl8, wbf, W1, W2, W3, b1, b2, b3, out, ra);
    } else {
        hashgrid_mlp<false><<<dim3(n / 256), dim3(256), 0, stream>>>(
            ipos, tables, tbl8, wbf, W1, W2, W3, b1, b2, b3, out, ra);
    }
}

// Round 14
// 463.000 us; speedup vs baseline: 2.8690x; 1.0407x over previous
//
#include <hip/hip_runtime.h>
#include <cmath>

typedef __attribute__((ext_vector_type(8))) short bf16x8;
typedef __attribute__((ext_vector_type(4))) float f32x4;
typedef __attribute__((ext_vector_type(2))) float f32x2;

#define TBLSZ (1 << 18)
#define TMASK (TBLSZ - 1)
#define N_ENTRIES ((long long)16 * TBLSZ)
#define FP8_SCALE 8192.0f
#define FP8_INV   (1.0f / 8192.0f)
#define FP4_SCALE 16384.0f
#define P2 2654435761u
#define P3 805459861u
#define N_DENSE 8
// ws layout: [tbl8 16MB][wbf 64KB][dense fp4 blocks ~16.3MB][feats8 64MB]
#define WS_TBL_BYTES (N_ENTRIES * 4)
#define WS_W_BYTES   (64 * 1024)
#define WS_TBL_NEED  (WS_TBL_BYTES + WS_W_BYTES)

struct ResArgs  { float r[16]; };
struct EncArgs  { float r[16]; int doff[16]; };      // doff: uint4 offset into dense, -1 = hashed
struct PrepArgs { int ncells[N_DENSE]; int doff[N_DENSE]; int resi[N_DENSE]; };

__device__ __forceinline__ unsigned short f2bf(float f) {
    unsigned u = __float_as_uint(f);
    u += 0x7fffu + ((u >> 16) & 1u);   // RTNE
    return (unsigned short)(u >> 16);
}

// ---- fp4 e2m1 quantize (input already scaled): code 0..7 = {0,.5,1,1.5,2,3,4,6} ----
__device__ __forceinline__ unsigned fp4q(float v) {
    float a = fabsf(v);
    unsigned c = 0;
    c += a >= 0.25f; c += a >= 0.75f; c += a >= 1.25f; c += a >= 1.75f;
    c += a >= 2.5f;  c += a >= 3.5f;  c += a >= 5.0f;
    return c | ((__float_as_uint(v) >> 28) & 8u);
}
// ---- fp4 e2m1 decode (returns value in scaled domain) ----
__device__ __forceinline__ float fp4d(unsigned nib) {
    unsigned e = (nib >> 1) & 3u, m = nib & 1u;
    unsigned u = e ? (((126u + e) << 23) | (m << 22)) : (m ? 0x3F000000u : 0u);
    u |= (nib & 8u) << 28;
    return __uint_as_float(u);
}

__device__ __forceinline__ unsigned sel4(uint4 W, unsigned i) {
    return (i & 2u) ? ((i & 1u) ? W.w : W.z) : ((i & 1u) ? W.y : W.x);
}

// ---- hashed level, fp8 tables, 16B-window x-pair (m<=3: both corners in window) ----
__device__ __forceinline__ unsigned enc_level_hashw(const unsigned* __restrict__ tbl,
                                                    float px, float py, float pz, float res) {
    float xl = px * res, yl = py * res, zl = pz * res;
    float fx = floorf(xl), fy = floorf(yl), fz = floorf(zl);
    float tx = xl - fx, ty = yl - fy, tz = zl - fz;
    unsigned cx = (unsigned)(int)fx, cy = (unsigned)(int)fy, cz = (unsigned)(int)fz;
    unsigned hy2[2] = { cy * P2, cy * P2 + P2 };
    unsigned hz2[2] = { cz * P3, cz * P3 + P3 };
    float wx[2] = { 1.f - tx, tx }, wy[2] = { 1.f - ty, ty }, wz[2] = { 1.f - tz, tz };
    const unsigned m = cx ^ (cx + 1u);          // 1,3,7,15,... (trailing-ones mask)
    const bool far = m > 3u;
    unsigned h0s[4], v0s[4], v1s[4];
    #pragma unroll
    for (int c = 0; c < 4; ++c) {               // c = oy*2+oz
        const int oy = (c >> 1) & 1, oz = c & 1;
        unsigned s  = hy2[oy] ^ hz2[oz];
        unsigned h0 = (cx ^ s) & TMASK;
        h0s[c] = h0;
        uint4 W = *(const uint4*)(tbl + (h0 & ~3u));   // aligned 16B window
        v0s[c] = sel4(W, h0 & 3u);
        v1s[c] = sel4(W, (h0 ^ m) & 3u);               // valid when m<=3
    }
    if (far) {                                  // 25% of cx: 4 masked loads
        #pragma unroll
        for (int c = 0; c < 4; ++c)
            v1s[c] = tbl[h0s[c] ^ m];
    }
    float a0 = 0.f, a1 = 0.f, a2 = 0.f, a3 = 0.f;
    #pragma unroll
    for (int c = 0; c < 4; ++c) {
        const int oy = (c >> 1) & 1, oz = c & 1;
        float w0 = wx[0] * wy[oy] * wz[oz];
        float w1 = wx[1] * wy[oy] * wz[oz];
        f32x2 lo0 = __builtin_amdgcn_cvt_pk_f32_fp8(v0s[c], false);
        f32x2 hi0 = __builtin_amdgcn_cvt_pk_f32_fp8(v0s[c], true);
        a0 = fmaf(w0, lo0[0], a0); a1 = fmaf(w0, lo0[1], a1);
        a2 = fmaf(w0, hi0[0], a2); a3 = fmaf(w0, hi0[1], a3);
        f32x2 lo1 = __builtin_amdgcn_cvt_pk_f32_fp8(v1s[c], false);
        f32x2 hi1 = __builtin_amdgcn_cvt_pk_f32_fp8(v1s[c], true);
        a0 = fmaf(w1, lo1[0], a0); a1 = fmaf(w1, lo1[1], a1);
        a2 = fmaf(w1, hi1[0], a2); a3 = fmaf(w1, hi1[1], a3);
    }
    int p = 0;
    p = __builtin_amdgcn_cvt_pk_fp8_f32(a0, a1, p, false);
    p = __builtin_amdgcn_cvt_pk_fp8_f32(a2, a3, p, true);
    return (unsigned)p;
}

// ---- dense level, fp4 blocks: one 16B load per point ----
__device__ __forceinline__ unsigned enc_level_dense4(const uint4* __restrict__ blk,
                                                     int resi, float px, float py, float pz, float res) {
    float xl = px * res, yl = py * res, zl = pz * res;
    float fx = floorf(xl), fy = floorf(yl), fz = floorf(zl);
    float tx = xl - fx, ty = yl - fy, tz = zl - fz;
    int cx = (int)fx, cy = (int)fy, cz = (int)fz;
    long long cell = ((long long)cx * resi + cy) * resi + cz;
    uint4 B = blk[cell];
    float wx[2] = { 1.f - tx, tx }, wy[2] = { 1.f - ty, ty }, wz[2] = { 1.f - tz, tz };
    unsigned wds[4] = { B.x, B.y, B.z, B.w };
    float a0 = 0.f, a1 = 0.f, a2 = 0.f, a3 = 0.f;
    #pragma unroll
    for (int c = 0; c < 8; ++c) {              // c = ox*4+oy*2+oz (matches prep pack)
        float ww = wx[(c >> 2) & 1] * wy[(c >> 1) & 1] * wz[c & 1];
        unsigned W = wds[c >> 1];
        const int sh = (c & 1) * 16;
        a0 = fmaf(ww, fp4d((W >> (sh +  0)) & 0xFu), a0);
        a1 = fmaf(ww, fp4d((W >> (sh +  4)) & 0xFu), a1);
        a2 = fmaf(ww, fp4d((W >> (sh +  8)) & 0xFu), a2);
        a3 = fmaf(ww, fp4d((W >> (sh + 12)) & 0xFu), a3);
    }
    // rescale FP4 domain -> FP8 domain (x 8192/16384)
    a0 *= 0.5f; a1 *= 0.5f; a2 *= 0.5f; a3 *= 0.5f;
    int p = 0;
    p = __builtin_amdgcn_cvt_pk_fp8_f32(a0, a1, p, false);
    p = __builtin_amdgcn_cvt_pk_fp8_f32(a2, a3, p, true);
    return (unsigned)p;
}

// ---- fallback helpers (bf16 feat output) ----
__device__ __forceinline__ uint2 enc_level_fp8(const unsigned* __restrict__ tbl,
                                               float px, float py, float pz, float res) {
    float xl = px * res, yl = py * res, zl = pz * res;
    float fx = floorf(xl), fy = floorf(yl), fz = floorf(zl);
    float tx = xl - fx, ty = yl - fy, tz = zl - fz;
    unsigned cx = (unsigned)(int)fx, cy = (unsigned)(int)fy, cz = (unsigned)(int)fz;
    unsigned hx[2] = { cx, cx + 1u };
    unsigned hy[2] = { cy * P2, cy * P2 + P2 };
    unsigned hz[2] = { cz * P3, cz * P3 + P3 };
    float wx[2] = { 1.f - tx, tx }, wy[2] = { 1.f - ty, ty }, wz[2] = { 1.f - tz, tz };
    float a0 = 0.f, a1 = 0.f, a2 = 0.f, a3 = 0.f;
    #pragma unroll
    for (int c = 0; c < 8; ++c) {
        const int ox = (c >> 2) & 1, oy = (c >> 1) & 1, oz = c & 1;
        unsigned h = (hx[ox] ^ hy[oy] ^ hz[oz]) & TMASK;
        unsigned v = tbl[h];
        float ww = wx[ox] * wy[oy] * wz[oz];
        f32x2 lo = __builtin_amdgcn_cvt_pk_f32_fp8(v, false);
        f32x2 hi = __builtin_amdgcn_cvt_pk_f32_fp8(v, true);
        a0 = fmaf(ww, lo[0], a0); a1 = fmaf(ww, lo[1], a1);
        a2 = fmaf(ww, hi[0], a2); a3 = fmaf(ww, hi[1], a3);
    }
    a0 *= FP8_INV; a1 *= FP8_INV; a2 *= FP8_INV; a3 *= FP8_INV;
    uint2 pk;
    pk.x = (unsigned)f2bf(a0) | ((unsigned)f2bf(a1) << 16);
    pk.y = (unsigned)f2bf(a2) | ((unsigned)f2bf(a3) << 16);
    return pk;
}

__device__ __forceinline__ uint2 enc_level_f32(const float4* __restrict__ tbl,
                                               float px, float py, float pz, float res) {
    float xl = px * res, yl = py * res, zl = pz * res;
    float fx = floorf(xl), fy = floorf(yl), fz = floorf(zl);
    float tx = xl - fx, ty = yl - fy, tz = zl - fz;
    unsigned cx = (unsigned)(int)fx, cy = (unsigned)(int)fy, cz = (unsigned)(int)fz;
    unsigned hx[2] = { cx, cx + 1u };
    unsigned hy[2] = { cy * P2, cy * P2 + P2 };
    unsigned hz[2] = { cz * P3, cz * P3 + P3 };
    float wx[2] = { 1.f - tx, tx }, wy[2] = { 1.f - ty, ty }, wz[2] = { 1.f - tz, tz };
    float a0 = 0.f, a1 = 0.f, a2 = 0.f, a3 = 0.f;
    #pragma unroll
    for (int c = 0; c < 8; ++c) {
        const int ox = (c >> 2) & 1, oy = (c >> 1) & 1, oz = c & 1;
        unsigned h = (hx[ox] ^ hy[oy] ^ hz[oz]) & TMASK;
        float4 v = tbl[h];
        float ww = wx[ox] * wy[oy] * wz[oz];
        a0 = fmaf(ww, v.x, a0); a1 = fmaf(ww, v.y, a1);
        a2 = fmaf(ww, v.z, a2); a3 = fmaf(ww, v.w, a3);
    }
    uint2 pk;
    pk.x = (unsigned)f2bf(a0) | ((unsigned)f2bf(a1) << 16);
    pk.y = (unsigned)f2bf(a2) | ((unsigned)f2bf(a3) << 16);
    return pk;
}

// ---- fused prologue: tbl8 conversion + weights + dense fp4 build (independent jobs) ----
__global__ __launch_bounds__(256) void prep(
    const float4* __restrict__ tables,
    const float* __restrict__ W1, const float* __restrict__ W2,
    const float* __restrict__ W3,
    unsigned* __restrict__ tbl8, unsigned short* __restrict__ wbf,
    uint4* __restrict__ dense, PrepArgs pa)
{
    const int gsz = gridDim.x * 256;
    const int gid = blockIdx.x * 256 + threadIdx.x;
    // A: all 16 levels f32 -> fp8 (x8192)
    for (long long i = gid; i < N_ENTRIES; i += gsz) {
        float4 v = tables[i];
        int p = 0;
        p = __builtin_amdgcn_cvt_pk_fp8_f32(v.x * FP8_SCALE, v.y * FP8_SCALE, p, false);
        p = __builtin_amdgcn_cvt_pk_fp8_f32(v.z * FP8_SCALE, v.w * FP8_SCALE, p, true);
        tbl8[i] = (unsigned)p;
    }
    // B: weights -> bf16
    if (blockIdx.x == 0) {
        const int t = threadIdx.x;
        const int base = t * 16;
        #pragma unroll
        for (int e = 0; e < 16; ++e) wbf[base + e] = f2bf(W1[base + e]);
        #pragma unroll
        for (int e = 0; e < 16; ++e) wbf[4096 + base + e] = f2bf(W2[base + e]);
        if (t < 32) {
            #pragma unroll
            for (int e = 0; e < 16; ++e) wbf[8192 + base + e] = f2bf(W3[base + e]);
        } else if (t < 64) {
            #pragma unroll
            for (int e = 0; e < 16; ++e) wbf[8192 + base + e] = 0;
        }
    }
    // C: dense fp4 blocks, levels 0..7, straight from f32 tables
    #pragma unroll 1
    for (int lvl = 0; lvl < N_DENSE; ++lvl) {
        const float4* tbl = tables + (size_t)lvl * TBLSZ;
        const int resi = pa.resi[lvl];
        uint4* dl = dense + pa.doff[lvl];
        for (int i = gid; i < pa.ncells[lvl]; i += gsz) {
            int cz = i % resi; int r = i / resi; int cy = r % resi; int cx = r / resi;
            unsigned w[4] = { 0, 0, 0, 0 };
            #pragma unroll
            for (int c = 0; c < 8; ++c) {              // c = ox*4+oy*2+oz
                unsigned hx = (unsigned)(cx + ((c >> 2) & 1));
                unsigned hy = (unsigned)(cy + ((c >> 1) & 1)) * P2;
                unsigned hz = (unsigned)(cz + (c & 1)) * P3;
                float4 v = tbl[(hx ^ hy ^ hz) & TMASK];
                unsigned n0 = fp4q(v.x * FP4_SCALE), n1 = fp4q(v.y * FP4_SCALE);
                unsigned n2 = fp4q(v.z * FP4_SCALE), n3 = fp4q(v.w * FP4_SCALE);
                const unsigned sh = (c & 1) * 16;
                w[c >> 1] |= (n0 << sh) | (n1 << (sh + 4)) | (n2 << (sh + 8)) | (n3 << (sh + 12));
            }
            uint4 o; o.x = w[0]; o.y = w[1]; o.z = w[2]; o.w = w[3];
            dl[i] = o;
        }
    }
}

// ---- phase 1: level-major encode; fp4-dense l<8 (1 req), hashed-window l>=8 (~5 req) ----
__global__ __launch_bounds__(256) void encode_lm(
    const float* __restrict__ ipos,
    const unsigned* __restrict__ tbl8,
    const uint4* __restrict__ dense,
    unsigned* __restrict__ feats8,       // [16][npts] fp8x4 (scaled 2^13)
    int chunks, int npts, EncArgs ea)
{
    const unsigned bid = blockIdx.x;
    const int lvl   = bid / (unsigned)chunks;
    const int chunk = bid - lvl * chunks;
    const long long pt = (long long)chunk * 256 + threadIdx.x;
    const float px = ipos[pt * 3 + 0];
    const float py = ipos[pt * 3 + 1];
    const float pz = ipos[pt * 3 + 2];
    const int doff = ea.doff[lvl];
    unsigned pk;
    if (doff >= 0)
        pk = enc_level_dense4(dense + doff, (int)ea.r[lvl], px, py, pz, ea.r[lvl]);
    else
        pk = enc_level_hashw(tbl8 + (size_t)lvl * TBLSZ, px, py, pz, ea.r[lvl]);
    feats8[(size_t)lvl * npts + pt] = pk;    // coalesced 4B store
}

// ---- phase 2: MLP via MFMA; fp8 feats -> bf16 B-frags via LDS transpose ----
__global__ __launch_bounds__(256, 4) void mlp_lm(
    const unsigned* __restrict__ feats8,
    const unsigned short* __restrict__ wbf,
    const float* __restrict__ b1, const float* __restrict__ b2,
    const float* __restrict__ b3,
    float* __restrict__ out, int npts)
{
    __shared__ __attribute__((aligned(16))) unsigned short xb[4][8][64][8];
    const int t   = threadIdx.x;
    const int w   = t >> 6;
    const int l   = t & 63;
    const int q   = l >> 4;
    const int l16 = l & 15;
    const long long gi = (long long)blockIdx.x * 256 + t;
    const int n2base = (l >> 4) * 2;

    #pragma unroll
    for (int lvl = 0; lvl < 16; ++lvl) {
        unsigned v = feats8[(size_t)lvl * npts + gi];
        f32x2 lo = __builtin_amdgcn_cvt_pk_f32_fp8(v, false);
        f32x2 hi = __builtin_amdgcn_cvt_pk_f32_fp8(v, true);
        uint2 pk;
        pk.x = (unsigned)f2bf(lo[0] * FP8_INV) | ((unsigned)f2bf(lo[1] * FP8_INV) << 16);
        pk.y = (unsigned)f2bf(hi[0] * FP8_INV) | ((unsigned)f2bf(hi[1] * FP8_INV) << 16);
        const int blk = n2base + (lvl >> 3);
        const int lp  = l16 + 16 * ((lvl & 7) >> 1);
        *(uint2*)&xb[w][blk][lp][(lvl & 1) * 4] = pk;
    }
    // no barrier: each wave reads only its own xb[w] blocks (DS in-order per wave)

    #pragma unroll 1
    for (int layer = 0; layer < 2; ++layer) {
        const float* bptr = layer ? b2 : b1;
        const unsigned short* wp = wbf + layer * 4096;
        f32x4 acc[4][4];
        #pragma unroll
        for (int m = 0; m < 4; ++m) {
            bf16x8 af0 = *(const bf16x8*)(wp + (m * 16 + l16) * 64 +  0 + q * 8);
            bf16x8 af1 = *(const bf16x8*)(wp + (m * 16 + l16) * 64 + 32 + q * 8);
            #pragma unroll
            for (int n = 0; n < 4; ++n) {
                f32x4 d = { 0.f, 0.f, 0.f, 0.f };
                d = __builtin_amdgcn_mfma_f32_16x16x32_bf16(af0, *(const bf16x8*)&xb[w][n * 2 + 0][l][0], d, 0, 0, 0);
                d = __builtin_amdgcn_mfma_f32_16x16x32_bf16(af1, *(const bf16x8*)&xb[w][n * 2 + 1][l][0], d, 0, 0, 0);
                acc[m][n] = d;
            }
        }
        #pragma unroll
        for (int m = 0; m < 4; ++m) {
            #pragma unroll
            for (int n = 0; n < 4; ++n) {
                #pragma unroll
                for (int rr = 0; rr < 4; rr += 2) {
                    const int j0 = m * 16 + q * 4 + rr;
                    float v0 = fmaxf(acc[m][n][rr]     + bptr[j0],     0.f);
                    float v1 = fmaxf(acc[m][n][rr + 1] + bptr[j0 + 1], 0.f);
                    unsigned pk = (unsigned)f2bf(v0) | ((unsigned)f2bf(v1) << 16);
                    const int blk = n * 2 + (j0 >> 5);
                    const int lp  = l16 + 16 * ((j0 & 31) >> 3);
                    *(unsigned*)&xb[w][blk][lp][j0 & 7] = pk;
                }
            }
        }
    }

    // layer 3 + sigmoid, coalesced f32x4 stores
    {
        bf16x8 af0 = *(const bf16x8*)(wbf + 8192 + l16 * 64 +  0 + q * 8);
        bf16x8 af1 = *(const bf16x8*)(wbf + 8192 + l16 * 64 + 32 + q * 8);
        const long long gbase = (long long)blockIdx.x * 256 + w * 64;
        #pragma unroll
        for (int n = 0; n < 4; ++n) {
            f32x4 d = { 0.f, 0.f, 0.f, 0.f };
            d = __builtin_amdgcn_mfma_f32_16x16x32_bf16(af0, *(const bf16x8*)&xb[w][n * 2 + 0][l][0], d, 0, 0, 0);
            d = __builtin_amdgcn_mfma_f32_16x16x32_bf16(af1, *(const bf16x8*)&xb[w][n * 2 + 1][l][0], d, 0, 0, 0);
            if (q < 2) {
                f32x4 o;
                #pragma unroll
                for (int r = 0; r < 4; ++r) {
                    float v = d[r] + b3[q * 4 + r];
                    o[r] = 1.f / (1.f + __expf(-v));
                }
                *(f32x4*)&out[(gbase + n * 16 + l16) * 8 + q * 4] = o;
            }
        }
    }
}

// ---- fallback: fused kernel, FP8 via ws or pure f32 ----
template<bool BF>
__global__ __launch_bounds__(256, 4) void hashgrid_mlp(
    const float* __restrict__ ipos,
    const float4* __restrict__ tables_f32,
    const unsigned* __restrict__ tbl8,
    const unsigned short* __restrict__ wbf,
    const float* __restrict__ W1, const float* __restrict__ W2,
    const float* __restrict__ W3,
    const float* __restrict__ b1, const float* __restrict__ b2,
    const float* __restrict__ b3,
    float* __restrict__ out, ResArgs ra)
{
    __shared__ __attribute__((aligned(16))) unsigned short xb[4][8][64][8];
    const int t   = threadIdx.x;
    const int w   = t >> 6;
    const int l   = t & 63;
    const int q   = l >> 4;
    const int l16 = l & 15;

    {
        const long long gi = (long long)blockIdx.x * 256 + t;
        const float px = ipos[gi * 3 + 0];
        const float py = ipos[gi * 3 + 1];
        const float pz = ipos[gi * 3 + 2];
        const int n2base = (l >> 4) * 2;
        #pragma unroll 2
        for (int lvl = 0; lvl < 16; ++lvl) {
            uint2 pk = BF ? enc_level_fp8(tbl8 + (size_t)lvl * TBLSZ, px, py, pz, ra.r[lvl])
                          : enc_level_f32(tables_f32 + (size_t)lvl * TBLSZ, px, py, pz, ra.r[lvl]);
            const int blk = n2base + (lvl >> 3);
            const int lp  = l16 + 16 * ((lvl & 7) >> 1);
            *(uint2*)&xb[w][blk][lp][(lvl & 1) * 4] = pk;
        }
    }

    #pragma unroll 1
    for (int layer = 0; layer < 2; ++layer) {
        const float* bptr = layer ? b2 : b1;
        f32x4 acc[4][4];
        #pragma unroll
        for (int m = 0; m < 4; ++m) {
            bf16x8 af0, af1;
            if constexpr (BF) {
                const unsigned short* wp = wbf + layer * 4096;
                af0 = *(const bf16x8*)(wp + (m * 16 + l16) * 64 +  0 + q * 8);
                af1 = *(const bf16x8*)(wp + (m * 16 + l16) * 64 + 32 + q * 8);
            } else {
                const float* Wp = layer ? W2 : W1;
                const float* r0 = Wp + (m * 16 + l16) * 64 + q * 8;
                float4 a = *(const float4*)(r0), b = *(const float4*)(r0 + 4);
                float4 c = *(const float4*)(r0 + 32), e = *(const float4*)(r0 + 36);
                af0[0]=f2bf(a.x);af0[1]=f2bf(a.y);af0[2]=f2bf(a.z);af0[3]=f2bf(a.w);
                af0[4]=f2bf(b.x);af0[5]=f2bf(b.y);af0[6]=f2bf(b.z);af0[7]=f2bf(b.w);
                af1[0]=f2bf(c.x);af1[1]=f2bf(c.y);af1[2]=f2bf(c.z);af1[3]=f2bf(c.w);
                af1[4]=f2bf(e.x);af1[5]=f2bf(e.y);af1[6]=f2bf(e.z);af1[7]=f2bf(e.w);
            }
            #pragma unroll
            for (int n = 0; n < 4; ++n) {
                f32x4 d = { 0.f, 0.f, 0.f, 0.f };
                d = __builtin_amdgcn_mfma_f32_16x16x32_bf16(af0, *(const bf16x8*)&xb[w][n * 2 + 0][l][0], d, 0, 0, 0);
                d = __builtin_amdgcn_mfma_f32_16x16x32_bf16(af1, *(const bf16x8*)&xb[w][n * 2 + 1][l][0], d, 0, 0, 0);
                acc[m][n] = d;
            }
        }
        #pragma unroll
        for (int m = 0; m < 4; ++m) {
            #pragma unroll
            for (int n = 0; n < 4; ++n) {
                #pragma unroll
                for (int rr = 0; rr < 4; rr += 2) {
                    const int j0 = m * 16 + q * 4 + rr;
                    float v0 = fmaxf(acc[m][n][rr]     + bptr[j0],     0.f);
                    float v1 = fmaxf(acc[m][n][rr + 1] + bptr[j0 + 1], 0.f);
                    unsigned pk = (unsigned)f2bf(v0) | ((unsigned)f2bf(v1) << 16);
                    const int blk = n * 2 + (j0 >> 5);
                    const int lp  = l16 + 16 * ((j0 & 31) >> 3);
                    *(unsigned*)&xb[w][blk][lp][j0 & 7] = pk;
                }
            }
        }
    }

    {
        bf16x8 af0, af1;
        if constexpr (BF) {
            af0 = *(const bf16x8*)(wbf + 8192 + l16 * 64 +  0 + q * 8);
            af1 = *(const bf16x8*)(wbf + 8192 + l16 * 64 + 32 + q * 8);
        } else {
            if (l16 < 8) {
                const float* r0 = W3 + l16 * 64 + q * 8;
                float4 a = *(const float4*)(r0), b = *(const float4*)(r0 + 4);
                float4 c = *(const float4*)(r0 + 32), e = *(const float4*)(r0 + 36);
                af0[0]=f2bf(a.x);af0[1]=f2bf(a.y);af0[2]=f2bf(a.z);af0[3]=f2bf(a.w);
                af0[4]=f2bf(b.x);af0[5]=f2bf(b.y);af0[6]=f2bf(b.z);af0[7]=f2bf(b.w);
                af1[0]=f2bf(c.x);af1[1]=f2bf(c.y);af1[2]=f2bf(c.z);af1[3]=f2bf(c.w);
                af1[4]=f2bf(e.x);af1[5]=f2bf(e.y);af1[6]=f2bf(e.z);af1[7]=f2bf(e.w);
            } else {
                af0 = bf16x8{0,0,0,0,0,0,0,0};
                af1 = bf16x8{0,0,0,0,0,0,0,0};
            }
        }
        const long long gbase = (long long)blockIdx.x * 256 + w * 64;
        #pragma unroll
        for (int n = 0; n < 4; ++n) {
            f32x4 d = { 0.f, 0.f, 0.f, 0.f };
            d = __builtin_amdgcn_mfma_f32_16x16x32_bf16(af0, *(const bf16x8*)&xb[w][n * 2 + 0][l][0], d, 0, 0, 0);
            d = __builtin_amdgcn_mfma_f32_16x16x32_bf16(af1, *(const bf16x8*)&xb[w][n * 2 + 1][l][0], d, 0, 0, 0);
            if (q < 2) {
                f32x4 o;
                #pragma unroll
                for (int r = 0; r < 4; ++r) {
                    float v = d[r] + b3[q * 4 + r];
                    o[r] = 1.f / (1.f + __expf(-v));
                }
                *(f32x4*)&out[(gbase + n * 16 + l16) * 8 + q * 4] = o;
            }
        }
    }
}

extern "C" void kernel_launch(void* const* d_in, const int* in_sizes, int n_in,
                              void* d_out, int out_size, void* d_ws, size_t ws_size,
                              hipStream_t stream) {
    const float*  ipos   = (const float*)d_in[0];
    const float4* tables = (const float4*)d_in[1];
    const float*  W1 = (const float*)d_in[2];
    const float*  b1 = (const float*)d_in[3];
    const float*  W2 = (const float*)d_in[4];
    const float*  b2 = (const float*)d_in[5];
    const float*  W3 = (const float*)d_in[6];
    const float*  b3 = (const float*)d_in[7];
    float* out = (float*)d_out;

    ResArgs ra;
    EncArgs ea;
    PrepArgs pa;
    const double g = exp((log(512.0) - log(16.0)) / 15.0);   // matches Python libm
    int resi[16];
    for (int lvl = 0; lvl < 16; ++lvl) {
        ra.r[lvl] = (float)floor(16.0 * pow(g, (double)lvl));
        ea.r[lvl] = ra.r[lvl];
        resi[lvl] = (int)ra.r[lvl];
    }

    const int n = in_sizes[0] / 3;           // 1<<20

    unsigned char* base = (unsigned char*)d_ws;
    unsigned* tbl8 = (unsigned*)base;
    unsigned short* wbf = (unsigned short*)(base + WS_TBL_BYTES);
    uint4* dense = (uint4*)(base + WS_TBL_BYTES + WS_W_BYTES);

    size_t dq = 0;                           // dense size in uint4 units
    for (int lvl = 0; lvl < 16; ++lvl) {
        if (lvl < N_DENSE) {
            ea.doff[lvl] = (int)dq;
            pa.doff[lvl] = (int)dq;
            long long c = (long long)resi[lvl] * resi[lvl] * resi[lvl];
            pa.ncells[lvl] = (int)c;
            pa.resi[lvl] = resi[lvl];
            dq += (size_t)c;
        } else {
            ea.doff[lvl] = -1;
        }
    }
    unsigned* feats8 = (unsigned*)(dense + dq);
    const size_t ws_full_need = (size_t)WS_TBL_BYTES + WS_W_BYTES + dq * 16
                              + (size_t)n * 16 * 4;

    if (ws_size >= ws_full_need) {           // ws_size constant per harness -> deterministic
        const int chunks = n / 256;          // 4096
        prep<<<dim3(8192), dim3(256), 0, stream>>>(tables, W1, W2, W3, tbl8, wbf, dense, pa);
        encode_lm<<<dim3(16 * chunks), dim3(256), 0, stream>>>(
            ipos, tbl8, dense, feats8, chunks, n, ea);
        mlp_lm<<<dim3(chunks), dim3(256), 0, stream>>>(feats8, wbf, b1, b2, b3, out, n);
    } else if (ws_size >= (size_t)WS_TBL_NEED) {
        prep<<<dim3(8192), dim3(256), 0, stream>>>(tables, W1, W2, W3, tbl8, wbf,
                                                   (uint4*)(base + WS_TBL_NEED), pa);
        hashgrid_mlp<true><<<dim3(n / 256), dim3(256), 0, stream>>>(
            ipos, tables, tbl8, wbf, W1, W2, W3, b1, b2, b3, out, ra);
    } else {
        hashgrid_mlp<false><<<dim3(n / 256), dim3(256), 0, stream>>>(
            ipos, tables, tbl8, wbf, W1, W2, W3, b1, b2, b3, out, ra);
    }
}